// Round 4
// baseline (2157.442 us; speedup 1.0000x reference)
//
#include <hip/hip_runtime.h>
#include <hip/hip_bf16.h>
#include <math.h>

#define BB 8192
#define FF 32
#define DD 128
#define HH 128
#define FD 4096   // F*D
#define E2 256    // 2*D
#define F2 8192   // 2*FD
#define LN_EPS 1e-5f
#define KS 4

typedef __hip_bfloat16 bf16;
__device__ __forceinline__ float b2f(bf16 v) { return __bfloat162float(v); }
__device__ __forceinline__ bf16 f2b(float v) { return __float2bfloat16(v); }

// ---------------- prep kernels (inputs fp32) ----------------

// A1[f,h] = sum_d Wp[f,d]*fW1[f,d,h]; C1[f,h] = sum_d bp[f,d]*fW1[f,d,h] + fb1[f,h]
__global__ void prep_A1(const float* __restrict__ Wp, const float* __restrict__ bp,
                        const float* __restrict__ fW1, const float* __restrict__ fb1,
                        float* __restrict__ A1, float* __restrict__ C1) {
  int f = blockIdx.x, h = threadIdx.x;
  const float* w1 = fW1 + (size_t)f * DD * HH;
  float a = 0.f, c = 0.f;
  for (int d = 0; d < DD; ++d) {
    float w = w1[d * HH + h];
    a += Wp[f * DD + d] * w;
    c += bp[f * DD + d] * w;
  }
  A1[f * HH + h] = a;
  C1[f * HH + h] = c + fb1[f * HH + h];
}

// M2[f,h,e] = sum_d fW2[f,h,d]*fWg[f,d,e]
__global__ void prep_M2(const float* __restrict__ fW2, const float* __restrict__ fWg,
                        float* __restrict__ M2) {
  int f = blockIdx.x, h = blockIdx.y, e = threadIdx.x;
  const float* w2 = fW2 + ((size_t)f * HH + h) * DD;
  const float* wg = fWg + (size_t)f * DD * E2;
  float acc = 0.f;
  for (int d = 0; d < DD; ++d) acc += w2[d] * wg[d * E2 + e];
  M2[((size_t)f * HH + h) * E2 + e] = acc;
}

// c2[f,e] = sum_d fb2[f,d]*fWg[f,d,e] + fbg[f,e]
__global__ void prep_c2(const float* __restrict__ fb2, const float* __restrict__ fWg,
                        const float* __restrict__ fbg, float* __restrict__ c2) {
  int f = blockIdx.x, e = threadIdx.x;
  const float* wg = fWg + (size_t)f * DD * E2;
  float acc = 0.f;
  for (int d = 0; d < DD; ++d) acc += fb2[f * DD + d] * wg[d * E2 + e];
  c2[f * E2 + e] = acc + fbg[f * E2 + e];
}

// M3 partials: M3[h,j] = sum_k sW2[h,k]*sWg[k,j], split-K by 4
__global__ void prep_M3(const float* __restrict__ sW2, const float* __restrict__ sWg,
                        float* __restrict__ M3p) {
  __shared__ float Bs[16][128];
  __shared__ float As[128][17];
  int j0 = blockIdx.x * 128;
  int k0 = blockIdx.y * (FD / KS);
  int tid = threadIdx.x;
  int tx = tid & 15, ty = tid >> 4;
  float acc[8][8];
  for (int i = 0; i < 8; ++i) for (int j = 0; j < 8; ++j) acc[i][j] = 0.f;
  for (int kc = 0; kc < FD / KS; kc += 16) {
    for (int t = tid; t < 2048; t += 256) {
      int r = t >> 7, c = t & 127;
      Bs[r][c] = sWg[(size_t)(k0 + kc + r) * F2 + j0 + c];
    }
    for (int t = tid; t < 2048; t += 256) {
      int h = t >> 4, k = t & 15;
      As[h][k] = sW2[(size_t)h * FD + k0 + kc + k];
    }
    __syncthreads();
    for (int k = 0; k < 16; ++k) {
      float bv[8], av[8];
      for (int jj = 0; jj < 8; ++jj) bv[jj] = Bs[k][tx + 16 * jj];
      for (int hh = 0; hh < 8; ++hh) av[hh] = As[ty + 16 * hh][k];
      for (int hh = 0; hh < 8; ++hh)
        for (int jj = 0; jj < 8; ++jj) acc[hh][jj] += av[hh] * bv[jj];
    }
    __syncthreads();
  }
  float* out = M3p + (size_t)blockIdx.y * DD * F2;
  for (int hh = 0; hh < 8; ++hh)
    for (int jj = 0; jj < 8; ++jj)
      out[(size_t)(ty + 16 * hh) * F2 + j0 + tx + 16 * jj] = acc[hh][jj];
}

__global__ void reduce_M3(const float* __restrict__ M3p, float* __restrict__ M3) {
  size_t i = (size_t)blockIdx.x * 256 + threadIdx.x;
  float s = 0.f;
  for (int ks = 0; ks < KS; ++ks) s += M3p[(size_t)ks * DD * F2 + i];
  M3[i] = s;
}

// c3 partials: c3[j] = sum_k sb2[k]*sWg[k,j] (+ sbg later)
__global__ void prep_c3_part(const float* __restrict__ sb2, const float* __restrict__ sWg,
                             float* __restrict__ c3p) {
  int j = blockIdx.x * 256 + threadIdx.x;
  int ks = blockIdx.y;
  const int kpb = FD / 8;
  float acc = 0.f;
  for (int k = ks * kpb; k < (ks + 1) * kpb; ++k) acc += sb2[k] * sWg[(size_t)k * F2 + j];
  c3p[(size_t)ks * F2 + j] = acc;
}

__global__ void reduce_c3(const float* __restrict__ c3p, const float* __restrict__ sbg,
                          float* __restrict__ c3) {
  int j = blockIdx.x * 256 + threadIdx.x;
  float s = sbg[j];
  for (int ks = 0; ks < 8; ++ks) s += c3p[(size_t)ks * F2 + j];
  c3[j] = s;
}

// ---------------- stage A: per-feature GRN + LN -> stacked (bf16) ----------------
__global__ void stageA(const float* __restrict__ x, const float* __restrict__ Wp,
                       const float* __restrict__ bp, const float* __restrict__ A1,
                       const float* __restrict__ C1, const float* __restrict__ M2,
                       const float* __restrict__ c2, const float* __restrict__ fg,
                       const float* __restrict__ fbe, bf16* __restrict__ stacked) {
  int f = blockIdx.y;
  int b0 = blockIdx.x * 16;
  int d = threadIdx.x;  // 0..127
  __shared__ float h1s[16][HH];
  __shared__ float red[2][2];
  float a1v = A1[f * HH + d], c1v = C1[f * HH + d];
  float xs[16];
  for (int r = 0; r < 16; ++r) {
    xs[r] = x[(b0 + r) * FF + f];
    float v = xs[r] * a1v + c1v;
    h1s[r][d] = v > 0.f ? v : expf(v) - 1.f;
  }
  __syncthreads();
  float a[16], s[16];
  float c2a = c2[f * E2 + d], c2s = c2[f * E2 + 128 + d];
  for (int r = 0; r < 16; ++r) { a[r] = c2a; s[r] = c2s; }
  const float* m2 = M2 + (size_t)f * HH * E2;
  for (int h = 0; h < HH; ++h) {
    float ma = m2[h * E2 + d];
    float ms = m2[h * E2 + 128 + d];
    for (int r = 0; r < 16; ++r) {
      float hv = h1s[r][h];
      a[r] += hv * ma;
      s[r] += hv * ms;
    }
  }
  float wpv = Wp[f * DD + d], bpv = bp[f * DD + d];
  float fgv = fg[f * DD + d], fbev = fbe[f * DD + d];
  int wid = d >> 6;
  for (int r = 0; r < 16; ++r) {
    float emb = xs[r] * wpv + bpv;
    float y = emb + a[r] * (1.f / (1.f + expf(-s[r])));
    float sum = y, sq = y * y;
    for (int off = 32; off; off >>= 1) {
      sum += __shfl_down(sum, off);
      sq += __shfl_down(sq, off);
    }
    if ((d & 63) == 0) { red[0][wid] = sum; red[1][wid] = sq; }
    __syncthreads();
    float mu = (red[0][0] + red[0][1]) * (1.f / DD);
    float var = (red[1][0] + red[1][1]) * (1.f / DD) - mu * mu;
    float rstd = rsqrtf(var + LN_EPS);
    stacked[((size_t)(b0 + r) * FF + f) * DD + d] = f2b((y - mu) * rstd * fgv + fbev);
    __syncthreads();
  }
}

// ---------------- K2: hh1 = elu(flat @ sW1 + sb1) ----------------
__global__ void sgrn1(const bf16* __restrict__ stacked, const float* __restrict__ sW1,
                      const float* __restrict__ sb1, float* __restrict__ hh1) {
  int b0 = blockIdx.x * 32;
  __shared__ float As[32][33];
  __shared__ float Bs[32][129];
  int tid = threadIdx.x;
  int tx = tid & 31, ty = tid >> 5;
  float acc[4][4] = {};
  for (int k0 = 0; k0 < FD; k0 += 32) {
    for (int i = 0; i < 4; ++i) {
      int t = tid + 256 * i; int r = t >> 5, k = t & 31;
      As[r][k] = b2f(stacked[(size_t)(b0 + r) * FD + k0 + k]);
    }
    for (int i = 0; i < 16; ++i) {
      int t = tid + 256 * i; int k = t >> 7, c = t & 127;
      Bs[k][c] = sW1[(size_t)(k0 + k) * HH + c];
    }
    __syncthreads();
    for (int k = 0; k < 32; ++k) {
      float av[4], bv[4];
      for (int rr = 0; rr < 4; ++rr) av[rr] = As[ty + 8 * rr][k];
      for (int cc = 0; cc < 4; ++cc) bv[cc] = Bs[k][tx + 32 * cc];
      for (int rr = 0; rr < 4; ++rr)
        for (int cc = 0; cc < 4; ++cc) acc[rr][cc] += av[rr] * bv[cc];
    }
    __syncthreads();
  }
  for (int rr = 0; rr < 4; ++rr)
    for (int cc = 0; cc < 4; ++cc) {
      int r = b0 + ty + 8 * rr, c = tx + 32 * cc;
      float v = acc[rr][cc] + sb1[c];
      hh1[r * HH + c] = v > 0.f ? v : expf(v) - 1.f;
    }
}

// ---------------- K3: tmp = flat + sa*sigmoid(ss), sgate = hh1@M3 + c3 fused ----------------
__global__ void sgate_fuse(const float* __restrict__ hh1, const float* __restrict__ M3,
                           const float* __restrict__ c3, const bf16* __restrict__ stacked,
                           bf16* __restrict__ tmp) {
  int b0 = blockIdx.x * 64;
  int c0 = blockIdx.y * 64;
  __shared__ float As[64][33];
  __shared__ float Ba[32][64];
  __shared__ float Bb[32][64];
  int tid = threadIdx.x;
  int tx = tid & 15, ty = tid >> 4;
  float accA[4][4] = {}, accB[4][4] = {};
  for (int k0 = 0; k0 < HH; k0 += 32) {
    for (int i = 0; i < 8; ++i) {
      int t = tid + 256 * i; int r = t >> 5, k = t & 31;
      As[r][k] = hh1[(b0 + r) * HH + k0 + k];
    }
    for (int i = 0; i < 8; ++i) {
      int t = tid + 256 * i; int k = t >> 6, c = t & 63;
      Ba[k][c] = M3[(size_t)(k0 + k) * F2 + c0 + c];
      Bb[k][c] = M3[(size_t)(k0 + k) * F2 + c0 + 4096 + c];
    }
    __syncthreads();
    for (int k = 0; k < 32; ++k) {
      float av[4], ba[4], bb[4];
      for (int rr = 0; rr < 4; ++rr) av[rr] = As[ty + 16 * rr][k];
      for (int cc = 0; cc < 4; ++cc) { ba[cc] = Ba[k][tx + 16 * cc]; bb[cc] = Bb[k][tx + 16 * cc]; }
      for (int rr = 0; rr < 4; ++rr)
        for (int cc = 0; cc < 4; ++cc) {
          accA[rr][cc] += av[rr] * ba[cc];
          accB[rr][cc] += av[rr] * bb[cc];
        }
    }
    __syncthreads();
  }
  for (int rr = 0; rr < 4; ++rr)
    for (int cc = 0; cc < 4; ++cc) {
      int r = b0 + ty + 16 * rr;
      int c = c0 + tx + 16 * cc;
      float sa = accA[rr][cc] + c3[c];
      float ss = accB[rr][cc] + c3[c + 4096];
      float g = 1.f / (1.f + expf(-ss));
      tmp[(size_t)r * FD + c] = f2b(b2f(stacked[(size_t)r * FD + c]) + sa * g);
    }
}

// ---------------- K4a: LN stats over tmp rows ----------------
__global__ void ln_stats(const bf16* __restrict__ tmp, float* __restrict__ rowstats) {
  int b = blockIdx.x;
  int tid = threadIdx.x;
  const bf16* row = tmp + (size_t)b * FD;
  float sum = 0.f, sq = 0.f;
  for (int j = tid; j < FD; j += 256) { float v = b2f(row[j]); sum += v; sq += v * v; }
  for (int off = 32; off; off >>= 1) { sum += __shfl_down(sum, off); sq += __shfl_down(sq, off); }
  __shared__ float rs[4], rq[4];
  int wid = tid >> 6;
  if ((tid & 63) == 0) { rs[wid] = sum; rq[wid] = sq; }
  __syncthreads();
  if (tid == 0) {
    float tot = rs[0] + rs[1] + rs[2] + rs[3];
    float totq = rq[0] + rq[1] + rq[2] + rq[3];
    float mu = tot * (1.f / FD);
    float var = totq * (1.f / FD) - mu * mu;
    rowstats[2 * b] = mu;
    rowstats[2 * b + 1] = rsqrtf(var + LN_EPS);
  }
}

// ---------------- K4b: logits = LN(tmp)*sg+sbe @ Wh + bh ----------------
__global__ void logits_k(const bf16* __restrict__ tmp, const float* __restrict__ rowstats,
                         const float* __restrict__ sg, const float* __restrict__ sbe,
                         const float* __restrict__ Wh, const float* __restrict__ bh,
                         float* __restrict__ logits) {
  int b0 = blockIdx.x * 64;
  __shared__ float As[64][33];
  __shared__ float Bs[32][33];
  __shared__ float mus[64], rstds[64];
  int tid = threadIdx.x;
  if (tid < 64) { mus[tid] = rowstats[2 * (b0 + tid)]; rstds[tid] = rowstats[2 * (b0 + tid) + 1]; }
  __syncthreads();
  int tx = tid & 31, ty = tid >> 5;
  float acc[8] = {};
  for (int k0 = 0; k0 < FD; k0 += 32) {
    for (int i = 0; i < 8; ++i) {
      int t = tid + 256 * i; int r = t >> 5, k = t & 31;
      float v = b2f(tmp[(size_t)(b0 + r) * FD + k0 + k]);
      As[r][k] = (v - mus[r]) * rstds[r] * sg[k0 + k] + sbe[k0 + k];
    }
    for (int i = 0; i < 4; ++i) {
      int t = tid + 256 * i; int k = t >> 5, c = t & 31;
      Bs[k][c] = Wh[(size_t)(k0 + k) * FF + c];
    }
    __syncthreads();
    for (int k = 0; k < 32; ++k) {
      float bv = Bs[k][tx];
      for (int rr = 0; rr < 8; ++rr) acc[rr] += As[ty + 8 * rr][k] * bv;
    }
    __syncthreads();
  }
  for (int rr = 0; rr < 8; ++rr) logits[(b0 + ty + 8 * rr) * FF + tx] = acc[rr] + bh[tx];
}

// ---------------- K4c: softmax -> weights (fp32 out) ----------------
__global__ void softmax_w(const float* __restrict__ logits, float* __restrict__ wfp32,
                          float* __restrict__ outw) {
  int tid = threadIdx.x;
  int b = blockIdx.x * 8 + (tid >> 5);
  int f = tid & 31;
  float l = logits[b * FF + f];
  float m = l;
  for (int off = 16; off; off >>= 1) m = fmaxf(m, __shfl_xor(m, off, 32));
  float e = expf(l - m);
  float s = e;
  for (int off = 16; off; off >>= 1) s += __shfl_xor(s, off, 32);
  float w = e / s;
  wfp32[b * FF + f] = w;
  outw[b * FF + f] = w;
}

// ---------------- K5: selected = sum_f stacked[b,f,:]*w[b,f] (fp32 out) ----------------
__global__ void select_k(const bf16* __restrict__ stacked, const float* __restrict__ wfp32,
                         float* __restrict__ outsel) {
  int b = blockIdx.x;
  int d = threadIdx.x;
  const bf16* srow = stacked + (size_t)b * FD;
  const float* wrow = wfp32 + b * FF;
  float acc = 0.f;
  for (int f = 0; f < FF; ++f) acc += b2f(srow[f * DD + d]) * wrow[f];
  outsel[b * DD + d] = acc;
}

extern "C" void kernel_launch(void* const* d_in, const int* in_sizes, int n_in,
                              void* d_out, int out_size, void* d_ws, size_t ws_size,
                              hipStream_t stream) {
  // Inputs fp32 (per reference); OUTPUT fp32 (per reference) — r1/r2 failed only
  // because we wrote bf16 into an fp32-read output buffer; r3's NaN came from
  // misreading fp32 inputs as bf16. See round-3 post-mortem dtype enumeration.
  const float* x   = (const float*)d_in[0];
  const float* Wp  = (const float*)d_in[1];
  const float* bp  = (const float*)d_in[2];
  const float* fW1 = (const float*)d_in[3];
  const float* fb1 = (const float*)d_in[4];
  const float* fW2 = (const float*)d_in[5];
  const float* fb2 = (const float*)d_in[6];
  const float* fWg = (const float*)d_in[7];
  const float* fbg = (const float*)d_in[8];
  const float* fg  = (const float*)d_in[9];
  const float* fbe = (const float*)d_in[10];
  const float* sW1 = (const float*)d_in[11];
  const float* sb1 = (const float*)d_in[12];
  const float* sW2 = (const float*)d_in[13];
  const float* sb2 = (const float*)d_in[14];
  const float* sWg = (const float*)d_in[15];
  const float* sbg = (const float*)d_in[16];
  const float* sg  = (const float*)d_in[17];
  const float* sbe = (const float*)d_in[18];
  const float* Wh  = (const float*)d_in[19];
  const float* bh  = (const float*)d_in[20];

  // workspace layout (total ~143 MB; r1's 286 MB layout also ran => ws_size >= 286MB)
  float* w = (float*)d_ws;
  size_t off = 0;
  float* A1   = w + off; off += (size_t)FF * HH;          // 4K
  float* C1   = w + off; off += (size_t)FF * HH;          // 4K
  float* c2   = w + off; off += (size_t)FF * E2;          // 8K
  float* c3   = w + off; off += (size_t)F2;               // 8K
  float* c3p  = w + off; off += (size_t)8 * F2;           // 64K
  float* rowstats = w + off; off += (size_t)2 * BB;       // 16K
  float* logits = w + off; off += (size_t)BB * FF;        // 256K
  float* wfp32  = w + off; off += (size_t)BB * FF;        // 256K
  float* M2   = w + off; off += (size_t)FF * HH * E2;     // 4 MB
  float* M3   = w + off; off += (size_t)DD * F2;          // 4 MB
  float* hh1  = w + off; off += (size_t)BB * HH;          // 4 MB
  bf16* stacked = (bf16*)(w + off); off += (size_t)BB * FD / 2;  // 64 MB
  // M3p (16 MB) aliases the tmp region: dead before tmp is written
  float* M3p = w + off;
  bf16* tmp  = (bf16*)(w + off); off += (size_t)BB * FD / 2;     // 64 MB

  float* outsel = (float*)d_out;
  float* outw   = outsel + (size_t)BB * DD;

  prep_A1<<<FF, 128, 0, stream>>>(Wp, bp, fW1, fb1, A1, C1);
  prep_M2<<<dim3(FF, HH), E2, 0, stream>>>(fW2, fWg, M2);
  prep_c2<<<FF, E2, 0, stream>>>(fb2, fWg, fbg, c2);
  prep_M3<<<dim3(F2 / 128, KS), 256, 0, stream>>>(sW2, sWg, M3p);
  reduce_M3<<<(DD * F2) / 256, 256, 0, stream>>>(M3p, M3);
  prep_c3_part<<<dim3(F2 / 256, 8), 256, 0, stream>>>(sb2, sWg, c3p);
  reduce_c3<<<F2 / 256, 256, 0, stream>>>(c3p, sbg, c3);
  stageA<<<dim3(BB / 16, FF), 128, 0, stream>>>(x, Wp, bp, A1, C1, M2, c2, fg, fbe, stacked);
  sgrn1<<<BB / 32, 256, 0, stream>>>(stacked, sW1, sb1, hh1);
  sgate_fuse<<<dim3(BB / 64, 4096 / 64), 256, 0, stream>>>(hh1, M3, c3, stacked, tmp);
  ln_stats<<<BB, 256, 0, stream>>>(tmp, rowstats);
  logits_k<<<BB / 64, 256, 0, stream>>>(tmp, rowstats, sg, sbe, Wh, bh, logits);
  softmax_w<<<BB / 8, 256, 0, stream>>>(logits, wfp32, outw);
  select_k<<<BB, 128, 0, stream>>>(stacked, wfp32, outsel);
}

// Round 5
// 1026.305 us; speedup vs baseline: 2.1021x; 2.1021x over previous
//
#include <hip/hip_runtime.h>
#include <hip/hip_bf16.h>
#include <math.h>

#define BB 8192
#define FF 32
#define DD 128
#define HH 128
#define FD 4096   // F*D
#define E2 256    // 2*D
#define F2 8192   // 2*FD
#define LN_EPS 1e-5f

typedef __hip_bfloat16 bf16;
typedef __attribute__((ext_vector_type(8))) short bf16x8;
typedef __attribute__((ext_vector_type(4))) float f32x4;

__device__ __forceinline__ float b2f(bf16 v) { return __bfloat162float(v); }
__device__ __forceinline__ bf16 f2b(float v) { return __float2bfloat16(v); }
__device__ __forceinline__ float s2f(short s) {
  union { float f; unsigned u; } x; x.u = ((unsigned)(unsigned short)s) << 16; return x.f;
}
__device__ __forceinline__ short f2s(float v) {
  bf16 h = __float2bfloat16(v); return *(short*)&h;
}

// ---------------- prep kernels (inputs fp32) ----------------

__global__ void prep_A1(const float* __restrict__ Wp, const float* __restrict__ bp,
                        const float* __restrict__ fW1, const float* __restrict__ fb1,
                        float* __restrict__ A1, float* __restrict__ C1) {
  int f = blockIdx.x, h = threadIdx.x;
  const float* w1 = fW1 + (size_t)f * DD * HH;
  float a = 0.f, c = 0.f;
  for (int d = 0; d < DD; ++d) {
    float w = w1[d * HH + h];
    a += Wp[f * DD + d] * w;
    c += bp[f * DD + d] * w;
  }
  A1[f * HH + h] = a;
  C1[f * HH + h] = c + fb1[f * HH + h];
}

__global__ void prep_M2(const float* __restrict__ fW2, const float* __restrict__ fWg,
                        float* __restrict__ M2) {
  int f = blockIdx.x, h = blockIdx.y, e = threadIdx.x;
  const float* w2 = fW2 + ((size_t)f * HH + h) * DD;
  const float* wg = fWg + (size_t)f * DD * E2;
  float acc = 0.f;
  for (int d = 0; d < DD; ++d) acc += w2[d] * wg[d * E2 + e];
  M2[((size_t)f * HH + h) * E2 + e] = acc;
}

__global__ void prep_c2(const float* __restrict__ fb2, const float* __restrict__ fWg,
                        const float* __restrict__ fbg, float* __restrict__ c2) {
  int f = blockIdx.x, e = threadIdx.x;
  const float* wg = fWg + (size_t)f * DD * E2;
  float acc = 0.f;
  for (int d = 0; d < DD; ++d) acc += fb2[f * DD + d] * wg[d * E2 + e];
  c2[f * E2 + e] = acc + fbg[f * E2 + e];
}

// elementwise fp32 -> bf16 cast (sW2)
__global__ void cast_bf16(const float* __restrict__ in, short* __restrict__ out, int n) {
  int i = blockIdx.x * 256 + threadIdx.x;
  if (i < n) out[i] = f2s(in[i]);
}

// transpose-cast: in (R x C) fp32 -> out (C x R) bf16
__global__ void castT(const float* __restrict__ in, short* __restrict__ out, int R, int C) {
  __shared__ float T[64][65];
  int c0 = blockIdx.x * 64, r0 = blockIdx.y * 64;
  int t = threadIdx.x;
  for (int i = 0; i < 16; ++i) {
    int idx = t + 256 * i; int r = idx >> 6, c = idx & 63;
    T[r][c] = in[(size_t)(r0 + r) * C + c0 + c];
  }
  __syncthreads();
  for (int i = 0; i < 16; ++i) {
    int idx = t + 256 * i; int c = idx >> 6, r = idx & 63;
    out[(size_t)(c0 + c) * R + r0 + r] = f2s(T[r][c]);
  }
}

// c3 init: c3[j] = sbg[j]
__global__ void c3_init(const float* __restrict__ sbg, float* __restrict__ c3) {
  int j = blockIdx.x * 256 + threadIdx.x;
  c3[j] = sbg[j];
}

// transpose-cast sWg (4096 x 8192) -> sWgT (8192 x 4096) bf16, fused c3 += sb2 @ sWg
__global__ void castT_c3(const float* __restrict__ in, short* __restrict__ out,
                         const float* __restrict__ sb2, float* __restrict__ c3) {
  __shared__ float T[64][65];
  int c0 = blockIdx.x * 64, r0 = blockIdx.y * 64;
  int t = threadIdx.x;
  for (int i = 0; i < 16; ++i) {
    int idx = t + 256 * i; int r = idx >> 6, c = idx & 63;
    T[r][c] = in[(size_t)(r0 + r) * F2 + c0 + c];
  }
  __syncthreads();
  for (int i = 0; i < 16; ++i) {
    int idx = t + 256 * i; int c = idx >> 6, r = idx & 63;
    out[(size_t)(c0 + c) * FD + r0 + r] = f2s(T[r][c]);
  }
  if (t < 64) {
    float s = 0.f;
    for (int r = 0; r < 64; ++r) s += sb2[r0 + r] * T[r][t];
    atomicAdd(&c3[c0 + t], s);
  }
}

// ---------------- MFMA GEMM: C[M,128] = A[M,K] @ BT[128,K]^T, split-K by 4 ----------------
// A row-major bf16, BT row-major bf16 (128 rows), partials fp32.
__global__ __launch_bounds__(256) void gemm_bt_n128_splitk(
    const short* __restrict__ A, const short* __restrict__ BT,
    float* __restrict__ Cp, int M, int K) {
  __shared__ short As[128 * 72];
  __shared__ short Bs[128 * 72];
  int m0 = blockIdx.x * 128;
  int kchunk = K >> 2;
  int kbase = blockIdx.y * kchunk;
  int tid = threadIdx.x;
  int lane = tid & 63, w = tid >> 6;
  int wm = (w >> 1) * 64, wn = (w & 1) * 64;
  int lm = lane & 15, lq = lane >> 4;
  f32x4 acc[4][4] = {};
  for (int kc = 0; kc < kchunk; kc += 64) {
    for (int i = 0; i < 4; ++i) {
      int li = tid + 256 * i;
      int r = li >> 3, c8 = (li & 7) * 8;
      *(bf16x8*)&As[r * 72 + c8] = *(const bf16x8*)&A[(size_t)(m0 + r) * K + kbase + kc + c8];
      *(bf16x8*)&Bs[r * 72 + c8] = *(const bf16x8*)&BT[(size_t)r * K + kbase + kc + c8];
    }
    __syncthreads();
    for (int ks = 0; ks < 2; ++ks) {
      bf16x8 af[4], bfr[4];
      for (int i = 0; i < 4; ++i)
        af[i] = *(const bf16x8*)&As[(wm + i * 16 + lm) * 72 + ks * 32 + lq * 8];
      for (int j = 0; j < 4; ++j)
        bfr[j] = *(const bf16x8*)&Bs[(wn + j * 16 + lm) * 72 + ks * 32 + lq * 8];
      for (int i = 0; i < 4; ++i)
        for (int j = 0; j < 4; ++j)
          acc[i][j] = __builtin_amdgcn_mfma_f32_16x16x32_bf16(af[i], bfr[j], acc[i][j], 0, 0, 0);
    }
    __syncthreads();
  }
  float* out = Cp + (size_t)blockIdx.y * M * 128;
  for (int i = 0; i < 4; ++i)
    for (int j = 0; j < 4; ++j)
      for (int v = 0; v < 4; ++v) {
        int r = wm + i * 16 + lq * 4 + v;
        int c = wn + j * 16 + lm;
        out[(size_t)(m0 + r) * 128 + c] = acc[i][j][v];
      }
}

// reduce split-K partials -> M3T bf16
__global__ void reduce_m3t(const float* __restrict__ Cp, short* __restrict__ M3T, int M) {
  size_t i = (size_t)blockIdx.x * 256 + threadIdx.x;
  float s = 0.f;
  for (int k = 0; k < 4; ++k) s += Cp[(size_t)k * M * 128 + i];
  M3T[i] = f2s(s);
}

// reduce split-K partials + bias + elu -> hh1 bf16
__global__ void reduce_hh1(const float* __restrict__ Cp, const float* __restrict__ sb1,
                           short* __restrict__ hh1, int M) {
  size_t i = (size_t)blockIdx.x * 256 + threadIdx.x;
  float s = 0.f;
  for (int k = 0; k < 4; ++k) s += Cp[(size_t)k * M * 128 + i];
  s += sb1[i & 127];
  hh1[i] = f2s(s > 0.f ? s : expf(s) - 1.f);
}

// ---------------- stage A: per-feature GRN + LN -> stacked (bf16) ----------------
__global__ void stageA(const float* __restrict__ x, const float* __restrict__ Wp,
                       const float* __restrict__ bp, const float* __restrict__ A1,
                       const float* __restrict__ C1, const float* __restrict__ M2,
                       const float* __restrict__ c2, const float* __restrict__ fg,
                       const float* __restrict__ fbe, bf16* __restrict__ stacked) {
  int f = blockIdx.y;
  int b0 = blockIdx.x * 16;
  int d = threadIdx.x;  // 0..127
  __shared__ float h1s[16][HH];
  __shared__ float red[2][2];
  float a1v = A1[f * HH + d], c1v = C1[f * HH + d];
  float xs[16];
  for (int r = 0; r < 16; ++r) {
    xs[r] = x[(b0 + r) * FF + f];
    float v = xs[r] * a1v + c1v;
    h1s[r][d] = v > 0.f ? v : expf(v) - 1.f;
  }
  __syncthreads();
  float a[16], s[16];
  float c2a = c2[f * E2 + d], c2s = c2[f * E2 + 128 + d];
  for (int r = 0; r < 16; ++r) { a[r] = c2a; s[r] = c2s; }
  const float* m2 = M2 + (size_t)f * HH * E2;
  for (int h = 0; h < HH; ++h) {
    float ma = m2[h * E2 + d];
    float ms = m2[h * E2 + 128 + d];
    for (int r = 0; r < 16; ++r) {
      float hv = h1s[r][h];
      a[r] += hv * ma;
      s[r] += hv * ms;
    }
  }
  float wpv = Wp[f * DD + d], bpv = bp[f * DD + d];
  float fgv = fg[f * DD + d], fbev = fbe[f * DD + d];
  int wid = d >> 6;
  for (int r = 0; r < 16; ++r) {
    float emb = xs[r] * wpv + bpv;
    float y = emb + a[r] * (1.f / (1.f + expf(-s[r])));
    float sum = y, sq = y * y;
    for (int off = 32; off; off >>= 1) {
      sum += __shfl_down(sum, off);
      sq += __shfl_down(sq, off);
    }
    if ((d & 63) == 0) { red[0][wid] = sum; red[1][wid] = sq; }
    __syncthreads();
    float mu = (red[0][0] + red[0][1]) * (1.f / DD);
    float var = (red[1][0] + red[1][1]) * (1.f / DD) - mu * mu;
    float rstd = rsqrtf(var + LN_EPS);
    stacked[((size_t)(b0 + r) * FF + f) * DD + d] = f2b((y - mu) * rstd * fgv + fbev);
    __syncthreads();
  }
}

// ---------------- sgate MFMA: gates = hh1 @ M3 (+c3), tmp = stacked + sa*sigmoid(ss) ----------------
// A = hh1 (M x 128), BT = M3T rows [c0..c0+64) (a-half) and [4096+c0..) (s-half). K=128.
__global__ __launch_bounds__(256) void sgate_mfma(
    const short* __restrict__ hh1, const short* __restrict__ M3T,
    const float* __restrict__ c3, const short* __restrict__ stacked,
    short* __restrict__ tmp) {
  __shared__ short As[128 * 72];
  __shared__ short Ba[64 * 72];
  __shared__ short Bb[64 * 72];
  int m0 = blockIdx.x * 128;
  int c0 = blockIdx.y * 64;
  int tid = threadIdx.x;
  int lane = tid & 63, w = tid >> 6;
  int wm = (w >> 1) * 64, wn = (w & 1) * 32;
  int lm = lane & 15, lq = lane >> 4;
  f32x4 accA[4][2] = {}, accB[4][2] = {};
  for (int kc = 0; kc < 128; kc += 64) {
    for (int i = 0; i < 4; ++i) {
      int li = tid + 256 * i;
      int r = li >> 3, c8 = (li & 7) * 8;
      *(bf16x8*)&As[r * 72 + c8] = *(const bf16x8*)&hh1[(size_t)(m0 + r) * 128 + kc + c8];
    }
    for (int i = 0; i < 2; ++i) {
      int li = tid + 256 * i;
      int r = li >> 3, c8 = (li & 7) * 8;
      *(bf16x8*)&Ba[r * 72 + c8] = *(const bf16x8*)&M3T[(size_t)(c0 + r) * 128 + kc + c8];
      *(bf16x8*)&Bb[r * 72 + c8] = *(const bf16x8*)&M3T[(size_t)(4096 + c0 + r) * 128 + kc + c8];
    }
    __syncthreads();
    for (int ks = 0; ks < 2; ++ks) {
      bf16x8 af[4], ba[2], bb[2];
      for (int i = 0; i < 4; ++i)
        af[i] = *(const bf16x8*)&As[(wm + i * 16 + lm) * 72 + ks * 32 + lq * 8];
      for (int j = 0; j < 2; ++j) {
        ba[j] = *(const bf16x8*)&Ba[(wn + j * 16 + lm) * 72 + ks * 32 + lq * 8];
        bb[j] = *(const bf16x8*)&Bb[(wn + j * 16 + lm) * 72 + ks * 32 + lq * 8];
      }
      for (int i = 0; i < 4; ++i)
        for (int j = 0; j < 2; ++j) {
          accA[i][j] = __builtin_amdgcn_mfma_f32_16x16x32_bf16(af[i], ba[j], accA[i][j], 0, 0, 0);
          accB[i][j] = __builtin_amdgcn_mfma_f32_16x16x32_bf16(af[i], bb[j], accB[i][j], 0, 0, 0);
        }
    }
    __syncthreads();
  }
  for (int i = 0; i < 4; ++i)
    for (int j = 0; j < 2; ++j)
      for (int v = 0; v < 4; ++v) {
        int r = m0 + wm + i * 16 + lq * 4 + v;
        int c = c0 + wn + j * 16 + lm;
        float sa = accA[i][j][v] + c3[c];
        float ss = accB[i][j][v] + c3[c + 4096];
        float g = 1.f / (1.f + expf(-ss));
        tmp[(size_t)r * FD + c] = f2s(s2f(stacked[(size_t)r * FD + c]) + sa * g);
      }
}

// ---------------- fused LN stats + normalize: normA = LN(tmp)*sg + sbe (bf16) ----------------
__global__ __launch_bounds__(256) void ln_norm(const short* __restrict__ tmp,
                                               const float* __restrict__ sg,
                                               const float* __restrict__ sbe,
                                               short* __restrict__ normA) {
  int b = blockIdx.x;
  int t = threadIdx.x;
  const short* row = tmp + (size_t)b * FD;
  float vals[16];
  {
    bf16x8 v0 = *(const bf16x8*)&row[t * 16];
    bf16x8 v1 = *(const bf16x8*)&row[t * 16 + 8];
    for (int i = 0; i < 8; ++i) { vals[i] = s2f(v0[i]); vals[8 + i] = s2f(v1[i]); }
  }
  float sum = 0.f, sq = 0.f;
  for (int i = 0; i < 16; ++i) { sum += vals[i]; sq += vals[i] * vals[i]; }
  for (int off = 32; off; off >>= 1) { sum += __shfl_down(sum, off); sq += __shfl_down(sq, off); }
  __shared__ float rs[4], rq[4];
  int wid = t >> 6;
  if ((t & 63) == 0) { rs[wid] = sum; rq[wid] = sq; }
  __syncthreads();
  float tot = rs[0] + rs[1] + rs[2] + rs[3];
  float totq = rq[0] + rq[1] + rq[2] + rq[3];
  float mu = tot * (1.f / FD);
  float var = totq * (1.f / FD) - mu * mu;
  float rstd = rsqrtf(var + LN_EPS);
  short outv[16];
  for (int i = 0; i < 16; ++i) {
    int j = t * 16 + i;
    outv[i] = f2s((vals[i] - mu) * rstd * sg[j] + sbe[j]);
  }
  *(bf16x8*)&normA[(size_t)b * FD + t * 16] = *(bf16x8*)&outv[0];
  *(bf16x8*)&normA[(size_t)b * FD + t * 16 + 8] = *(bf16x8*)&outv[8];
}

// ---------------- logits = normA @ Wh + bh (32-row tiles, 256 blocks) ----------------
__global__ void logits_k2(const short* __restrict__ normA, const float* __restrict__ Wh,
                          const float* __restrict__ bh, float* __restrict__ logits) {
  int b0 = blockIdx.x * 32;
  __shared__ float As[32][33];
  __shared__ float Bs[32][33];
  int tid = threadIdx.x;
  int tx = tid & 31, ty = tid >> 5;  // ty 0..7
  float acc[4] = {};
  for (int k0 = 0; k0 < FD; k0 += 32) {
    for (int i = 0; i < 4; ++i) {
      int tt = tid + 256 * i; int r = tt >> 5, k = tt & 31;
      As[r][k] = s2f(normA[(size_t)(b0 + r) * FD + k0 + k]);
    }
    for (int i = 0; i < 4; ++i) {
      int tt = tid + 256 * i; int k = tt >> 5, c = tt & 31;
      Bs[k][c] = Wh[(size_t)(k0 + k) * FF + c];
    }
    __syncthreads();
    for (int k = 0; k < 32; ++k) {
      float bv = Bs[k][tx];
      for (int rr = 0; rr < 4; ++rr) acc[rr] += As[ty + 8 * rr][k] * bv;
    }
    __syncthreads();
  }
  for (int rr = 0; rr < 4; ++rr) logits[(b0 + ty + 8 * rr) * FF + tx] = acc[rr] + bh[tx];
}

// ---------------- softmax -> weights (fp32 out) ----------------
__global__ void softmax_w(const float* __restrict__ logits, float* __restrict__ wfp32,
                          float* __restrict__ outw) {
  int tid = threadIdx.x;
  int b = blockIdx.x * 8 + (tid >> 5);
  int f = tid & 31;
  float l = logits[b * FF + f];
  float m = l;
  for (int off = 16; off; off >>= 1) m = fmaxf(m, __shfl_xor(m, off, 32));
  float e = expf(l - m);
  float s = e;
  for (int off = 16; off; off >>= 1) s += __shfl_xor(s, off, 32);
  float w = e / s;
  wfp32[b * FF + f] = w;
  outw[b * FF + f] = w;
}

// ---------------- selected = sum_f stacked[b,f,:]*w[b,f] (fp32 out) ----------------
__global__ void select_k(const bf16* __restrict__ stacked, const float* __restrict__ wfp32,
                         float* __restrict__ outsel) {
  int b = blockIdx.x;
  int d = threadIdx.x;
  const bf16* srow = stacked + (size_t)b * FD;
  const float* wrow = wfp32 + b * FF;
  float acc = 0.f;
  for (int f = 0; f < FF; ++f) acc += b2f(srow[f * DD + d]) * wrow[f];
  outsel[b * DD + d] = acc;
}

extern "C" void kernel_launch(void* const* d_in, const int* in_sizes, int n_in,
                              void* d_out, int out_size, void* d_ws, size_t ws_size,
                              hipStream_t stream) {
  const float* x   = (const float*)d_in[0];
  const float* Wp  = (const float*)d_in[1];
  const float* bp  = (const float*)d_in[2];
  const float* fW1 = (const float*)d_in[3];
  const float* fb1 = (const float*)d_in[4];
  const float* fW2 = (const float*)d_in[5];
  const float* fb2 = (const float*)d_in[6];
  const float* fWg = (const float*)d_in[7];
  const float* fbg = (const float*)d_in[8];
  const float* fg  = (const float*)d_in[9];
  const float* fbe = (const float*)d_in[10];
  const float* sW1 = (const float*)d_in[11];
  const float* sb1 = (const float*)d_in[12];
  const float* sW2 = (const float*)d_in[13];
  const float* sb2 = (const float*)d_in[14];
  const float* sWg = (const float*)d_in[15];
  const float* sbg = (const float*)d_in[16];
  const float* sg  = (const float*)d_in[17];
  const float* sbe = (const float*)d_in[18];
  const float* Wh  = (const float*)d_in[19];
  const float* bh  = (const float*)d_in[20];

  // workspace layout (~230 MB; ws_size >= 286 MB established in r1)
  float* w = (float*)d_ws;
  size_t off = 0;
  float* A1   = w + off; off += (size_t)FF * HH;
  float* C1   = w + off; off += (size_t)FF * HH;
  float* c2   = w + off; off += (size_t)FF * E2;
  float* c3   = w + off; off += (size_t)F2;
  float* logits = w + off; off += (size_t)BB * FF;
  float* wfp32  = w + off; off += (size_t)BB * FF;
  float* M2   = w + off; off += (size_t)FF * HH * E2;              // 4 MB
  float* partial = w + off; off += (size_t)4 * BB * 128;           // 16 MB (split-K, reused G1/G2)
  short* hh1  = (short*)(w + off); off += (size_t)BB * 128 / 2;    // 2 MB bf16
  short* M3T  = (short*)(w + off); off += (size_t)F2 * 128 / 2;    // 2 MB bf16
  short* sW2b = (short*)(w + off); off += (size_t)128 * FD / 2;    // 1 MB bf16
  short* sW1T = (short*)(w + off); off += (size_t)128 * FD / 2;    // 1 MB bf16
  short* stacked = (short*)(w + off); off += (size_t)BB * FD / 2;  // 64 MB bf16
  short* tmp  = (short*)(w + off); off += (size_t)BB * FD / 2;     // 64 MB bf16
  // sWgT (64 MB) dead after G1; normA aliases it
  short* sWgT  = (short*)(w + off);
  short* normA = (short*)(w + off); off += (size_t)F2 * FD / 2;    // 64 MB bf16

  float* outsel = (float*)d_out;
  float* outw   = outsel + (size_t)BB * DD;

  // --- prep / casts ---
  cast_bf16<<<(128 * FD + 255) / 256, 256, 0, stream>>>(sW2, sW2b, 128 * FD);
  castT<<<dim3(DD / 64, FD / 64), 256, 0, stream>>>(sW1, sW1T, FD, DD);   // sW1 (4096x128) -> (128x4096)
  c3_init<<<F2 / 256, 256, 0, stream>>>(sbg, c3);
  castT_c3<<<dim3(F2 / 64, FD / 64), 256, 0, stream>>>(sWg, sWgT, sb2, c3);
  // --- G1: M3T = (sW2 @ sWg)^T via sWgT(8192x4096) x sW2b(128x4096)^T ---
  gemm_bt_n128_splitk<<<dim3(F2 / 128, 4), 256, 0, stream>>>(sWgT, sW2b, partial, F2, FD);
  reduce_m3t<<<(F2 * 128) / 256, 256, 0, stream>>>(partial, M3T, F2);
  // --- per-feature GRN prep + stage A ---
  prep_A1<<<FF, 128, 0, stream>>>(Wp, bp, fW1, fb1, A1, C1);
  prep_M2<<<dim3(FF, HH), E2, 0, stream>>>(fW2, fWg, M2);
  prep_c2<<<FF, E2, 0, stream>>>(fb2, fWg, fbg, c2);
  stageA<<<dim3(BB / 16, FF), 128, 0, stream>>>(x, Wp, bp, A1, C1, M2, c2, fg, fbe,
                                                (bf16*)stacked);
  // --- G2: hh1 = elu(stacked @ sW1 + sb1) ---
  gemm_bt_n128_splitk<<<dim3(BB / 128, 4), 256, 0, stream>>>(stacked, sW1T, partial, BB, FD);
  reduce_hh1<<<(BB * 128) / 256, 256, 0, stream>>>(partial, sb1, hh1, BB);
  // --- G3: tmp = stacked + sa*sigmoid(ss) ---
  sgate_mfma<<<dim3(BB / 128, FD / 64), 256, 0, stream>>>(hh1, M3T, c3, stacked, tmp);
  // --- LN + logits + softmax + select ---
  ln_norm<<<BB, 256, 0, stream>>>(tmp, sg, sbe, normA);
  logits_k2<<<BB / 32, 256, 0, stream>>>(normA, Wh, bh, logits);
  softmax_w<<<BB / 8, 256, 0, stream>>>(logits, wfp32, outw);
  select_k<<<BB, 128, 0, stream>>>((const bf16*)stacked, wfp32, outsel);
}

// Round 6
// 618.244 us; speedup vs baseline: 3.4896x; 1.6600x over previous
//
#include <hip/hip_runtime.h>
#include <hip/hip_bf16.h>
#include <math.h>

#define BB 8192
#define FF 32
#define DD 128
#define HH 128
#define FD 4096   // F*D
#define E2 256    // 2*D
#define F2 8192   // 2*FD
#define LN_EPS 1e-5f

typedef __hip_bfloat16 bf16;
typedef __attribute__((ext_vector_type(8))) short bf16x8;
typedef __attribute__((ext_vector_type(4))) float f32x4;

__device__ __forceinline__ float b2f(bf16 v) { return __bfloat162float(v); }
__device__ __forceinline__ float s2f(short s) {
  union { float f; unsigned u; } x; x.u = ((unsigned)(unsigned short)s) << 16; return x.f;
}
__device__ __forceinline__ short f2s(float v) {
  bf16 h = __float2bfloat16(v); return *(short*)&h;
}

// ---------------- prep kernels (inputs fp32) ----------------

__global__ void prep_A1(const float* __restrict__ Wp, const float* __restrict__ bp,
                        const float* __restrict__ fW1, const float* __restrict__ fb1,
                        float* __restrict__ A1, float* __restrict__ C1) {
  int f = blockIdx.x, h = threadIdx.x;
  const float* w1 = fW1 + (size_t)f * DD * HH;
  float a = 0.f, c = 0.f;
  for (int d = 0; d < DD; ++d) {
    float w = w1[d * HH + h];
    a += Wp[f * DD + d] * w;
    c += bp[f * DD + d] * w;
  }
  A1[f * HH + h] = a;
  C1[f * HH + h] = c + fb1[f * HH + h];
}

__global__ void prep_M2(const float* __restrict__ fW2, const float* __restrict__ fWg,
                        float* __restrict__ M2) {
  int f = blockIdx.x, h = blockIdx.y, e = threadIdx.x;
  const float* w2 = fW2 + ((size_t)f * HH + h) * DD;
  const float* wg = fWg + (size_t)f * DD * E2;
  float acc = 0.f;
  for (int d = 0; d < DD; ++d) acc += w2[d] * wg[d * E2 + e];
  M2[((size_t)f * HH + h) * E2 + e] = acc;
}

// M2 [f][h][e] fp32 -> M2T [f][e][h] bf16
__global__ void m2_castT(const float* __restrict__ M2, short* __restrict__ M2T) {
  __shared__ float T[64][65];
  int h0 = blockIdx.x * 64, e0 = blockIdx.y * 64, f = blockIdx.z;
  int t = threadIdx.x;
  for (int i = 0; i < 16; ++i) {
    int idx = t + 256 * i; int r = idx >> 6, c = idx & 63;
    T[r][c] = M2[((size_t)f * HH + h0 + r) * E2 + e0 + c];
  }
  __syncthreads();
  for (int i = 0; i < 16; ++i) {
    int idx = t + 256 * i; int e = idx >> 6, h = idx & 63;
    M2T[((size_t)f * E2 + e0 + e) * HH + h0 + h] = f2s(T[h][e]);
  }
}

__global__ void prep_c2(const float* __restrict__ fb2, const float* __restrict__ fWg,
                        const float* __restrict__ fbg, float* __restrict__ c2) {
  int f = blockIdx.x, e = threadIdx.x;
  const float* wg = fWg + (size_t)f * DD * E2;
  float acc = 0.f;
  for (int d = 0; d < DD; ++d) acc += fb2[f * DD + d] * wg[d * E2 + e];
  c2[f * E2 + e] = acc + fbg[f * E2 + e];
}

__global__ void cast_bf16(const float* __restrict__ in, short* __restrict__ out, int n) {
  int i = blockIdx.x * 256 + threadIdx.x;
  if (i < n) out[i] = f2s(in[i]);
}

// transpose-cast: in (R x C) fp32 -> out (C x R) bf16
__global__ void castT(const float* __restrict__ in, short* __restrict__ out, int R, int C) {
  __shared__ float T[64][65];
  int c0 = blockIdx.x * 64, r0 = blockIdx.y * 64;
  int t = threadIdx.x;
  for (int i = 0; i < 16; ++i) {
    int idx = t + 256 * i; int r = idx >> 6, c = idx & 63;
    T[r][c] = in[(size_t)(r0 + r) * C + c0 + c];
  }
  __syncthreads();
  for (int i = 0; i < 16; ++i) {
    int idx = t + 256 * i; int c = idx >> 6, r = idx & 63;
    out[(size_t)(c0 + c) * R + r0 + r] = f2s(T[r][c]);
  }
}

__global__ void c3_init(const float* __restrict__ sbg, float* __restrict__ c3) {
  int j = blockIdx.x * 256 + threadIdx.x;
  c3[j] = sbg[j];
}

// transpose-cast sWg (4096 x 8192) -> sWgT (8192 x 4096) bf16, fused c3 += sb2 @ sWg
__global__ void castT_c3(const float* __restrict__ in, short* __restrict__ out,
                         const float* __restrict__ sb2, float* __restrict__ c3) {
  __shared__ float T[64][65];
  int c0 = blockIdx.x * 64, r0 = blockIdx.y * 64;
  int t = threadIdx.x;
  for (int i = 0; i < 16; ++i) {
    int idx = t + 256 * i; int r = idx >> 6, c = idx & 63;
    T[r][c] = in[(size_t)(r0 + r) * F2 + c0 + c];
  }
  __syncthreads();
  for (int i = 0; i < 16; ++i) {
    int idx = t + 256 * i; int c = idx >> 6, r = idx & 63;
    out[(size_t)(c0 + c) * FD + r0 + r] = f2s(T[r][c]);
  }
  if (t < 64) {
    float s = 0.f;
    for (int r = 0; r < 64; ++r) s += sb2[r0 + r] * T[r][t];
    atomicAdd(&c3[c0 + t], s);
  }
}

// u/w0 init and WhS = sg*Wh transpose-cast, u = sg.Wh, w0 = sbe.Wh + bh
__global__ void whs_init(const float* __restrict__ bh, float* __restrict__ u,
                         float* __restrict__ w0) {
  int c = threadIdx.x;
  u[c] = 0.f;
  w0[c] = bh[c];
}

__global__ void prep_whs(const float* __restrict__ Wh, const float* __restrict__ sg,
                         const float* __restrict__ sbe, short* __restrict__ WhS,
                         float* __restrict__ u, float* __restrict__ w0) {
  __shared__ float T[64][33];
  int k0 = blockIdx.x * 64;
  int t = threadIdx.x;
  {
    int k = t >> 5, c = t & 31;
    for (int i = 0; i < 8; ++i)
      T[k + 8 * i][c] = Wh[(size_t)(k0 + k + 8 * i) * FF + c];
  }
  __syncthreads();
  {
    int c = t >> 3, kk = (t & 7) * 8;
    short o[8];
    for (int i = 0; i < 8; ++i) o[i] = f2s(sg[k0 + kk + i] * T[kk + i][c]);
    *(bf16x8*)&WhS[(size_t)c * FD + k0 + kk] = *(bf16x8*)&o[0];
  }
  if (t < 32) {
    float su = 0.f, sw = 0.f;
    for (int k = 0; k < 64; ++k) { su += sg[k0 + k] * T[k][t]; sw += sbe[k0 + k] * T[k][t]; }
    atomicAdd(&u[t], su);
    atomicAdd(&w0[t], sw);
  }
}

// ---------------- MFMA GEMM: C[M,128] = A[M,K] @ BT[128,K]^T, split-K by 4 ----------------
__global__ __launch_bounds__(256) void gemm_bt_n128_splitk(
    const short* __restrict__ A, const short* __restrict__ BT,
    float* __restrict__ Cp, int M, int K) {
  __shared__ short As[128 * 72];
  __shared__ short Bs[128 * 72];
  int m0 = blockIdx.x * 128;
  int kchunk = K >> 2;
  int kbase = blockIdx.y * kchunk;
  int tid = threadIdx.x;
  int lane = tid & 63, w = tid >> 6;
  int wm = (w >> 1) * 64, wn = (w & 1) * 64;
  int lm = lane & 15, lq = lane >> 4;
  f32x4 acc[4][4] = {};
  for (int kc = 0; kc < kchunk; kc += 64) {
    for (int i = 0; i < 4; ++i) {
      int li = tid + 256 * i;
      int r = li >> 3, c8 = (li & 7) * 8;
      *(bf16x8*)&As[r * 72 + c8] = *(const bf16x8*)&A[(size_t)(m0 + r) * K + kbase + kc + c8];
      *(bf16x8*)&Bs[r * 72 + c8] = *(const bf16x8*)&BT[(size_t)r * K + kbase + kc + c8];
    }
    __syncthreads();
    for (int ks = 0; ks < 2; ++ks) {
      bf16x8 af[4], bfr[4];
      for (int i = 0; i < 4; ++i)
        af[i] = *(const bf16x8*)&As[(wm + i * 16 + lm) * 72 + ks * 32 + lq * 8];
      for (int j = 0; j < 4; ++j)
        bfr[j] = *(const bf16x8*)&Bs[(wn + j * 16 + lm) * 72 + ks * 32 + lq * 8];
      for (int i = 0; i < 4; ++i)
        for (int j = 0; j < 4; ++j)
          acc[i][j] = __builtin_amdgcn_mfma_f32_16x16x32_bf16(af[i], bfr[j], acc[i][j], 0, 0, 0);
    }
    __syncthreads();
  }
  float* out = Cp + (size_t)blockIdx.y * M * 128;
  for (int i = 0; i < 4; ++i)
    for (int j = 0; j < 4; ++j)
      for (int v = 0; v < 4; ++v) {
        int r = wm + i * 16 + lq * 4 + v;
        int c = wn + j * 16 + lm;
        out[(size_t)(m0 + r) * 128 + c] = acc[i][j][v];
      }
}

__global__ void reduce_m3t(const float* __restrict__ Cp, short* __restrict__ M3T, int M) {
  size_t i = (size_t)blockIdx.x * 256 + threadIdx.x;
  float s = 0.f;
  for (int k = 0; k < 4; ++k) s += Cp[(size_t)k * M * 128 + i];
  M3T[i] = f2s(s);
}

__global__ void reduce_hh1(const float* __restrict__ Cp, const float* __restrict__ sb1,
                           short* __restrict__ hh1, int M) {
  size_t i = (size_t)blockIdx.x * 256 + threadIdx.x;
  float s = 0.f;
  for (int k = 0; k < 4; ++k) s += Cp[(size_t)k * M * 128 + i];
  s += sb1[i & 127];
  hh1[i] = f2s(s > 0.f ? s : expf(s) - 1.f);
}

// ---------------- stage A (MFMA): h1 = elu(x*A1+C1); gates = h1@M2; LN -> stacked ----------------
// grid (BB/128, FF). Dual-half accumulators (a: e=c, s: e=c+128), LN epilogue.
__global__ __launch_bounds__(256) void stageA_mfma(
    const float* __restrict__ x, const float* __restrict__ Wp,
    const float* __restrict__ bp, const float* __restrict__ A1,
    const float* __restrict__ C1, const short* __restrict__ M2T,
    const float* __restrict__ c2, const float* __restrict__ fg,
    const float* __restrict__ fbe, short* __restrict__ stacked) {
  __shared__ short As[128 * 72];   // h1 tile [row][k-chunk]
  __shared__ short Ba[128 * 72];   // M2T rows 0..127 (a-half)
  __shared__ short Bb[128 * 72];   // M2T rows 128..255 (s-half)
  __shared__ float red[2][128][2];
  int f = blockIdx.y;
  int m0 = blockIdx.x * 128;
  int tid = threadIdx.x;
  int lane = tid & 63, w = tid >> 6;
  int wm = (w >> 1) * 64, wn = (w & 1) * 64;
  int lm = lane & 15, lq = lane >> 4;
  f32x4 accA[4][4] = {}, accB[4][4] = {};
  for (int kc = 0; kc < HH; kc += 64) {
    // compute h1 chunk into As (bf16): each thread one row, 32 h values
    {
      int r = tid >> 1;
      int hcb = (tid & 1) * 32;
      float xr = x[(size_t)(m0 + r) * FF + f];
      const float* a1p = A1 + f * HH + kc + hcb;
      const float* c1p = C1 + f * HH + kc + hcb;
      short* dst = &As[r * 72 + hcb];
      for (int s = 0; s < 32; ++s) {
        float v = xr * a1p[s] + c1p[s];
        dst[s] = f2s(v > 0.f ? v : expf(v) - 1.f);
      }
    }
    // stage M2T halves
    for (int i = 0; i < 4; ++i) {
      int li = tid + 256 * i;
      int rr = li >> 3, c8 = (li & 7) * 8;
      *(bf16x8*)&Ba[rr * 72 + c8] = *(const bf16x8*)&M2T[((size_t)f * E2 + rr) * HH + kc + c8];
      *(bf16x8*)&Bb[rr * 72 + c8] = *(const bf16x8*)&M2T[((size_t)f * E2 + 128 + rr) * HH + kc + c8];
    }
    __syncthreads();
    for (int ks = 0; ks < 2; ++ks) {
      bf16x8 af[4], ba[4], bb[4];
      for (int i = 0; i < 4; ++i)
        af[i] = *(const bf16x8*)&As[(wm + i * 16 + lm) * 72 + ks * 32 + lq * 8];
      for (int j = 0; j < 4; ++j) {
        ba[j] = *(const bf16x8*)&Ba[(wn + j * 16 + lm) * 72 + ks * 32 + lq * 8];
        bb[j] = *(const bf16x8*)&Bb[(wn + j * 16 + lm) * 72 + ks * 32 + lq * 8];
      }
      for (int i = 0; i < 4; ++i)
        for (int j = 0; j < 4; ++j) {
          accA[i][j] = __builtin_amdgcn_mfma_f32_16x16x32_bf16(af[i], ba[j], accA[i][j], 0, 0, 0);
          accB[i][j] = __builtin_amdgcn_mfma_f32_16x16x32_bf16(af[i], bb[j], accB[i][j], 0, 0, 0);
        }
    }
    __syncthreads();
  }
  // epilogue: gating + LN
  float c2a[4], c2s[4], wpv[4], bpv[4], fgv[4], fbev[4];
  for (int j = 0; j < 4; ++j) {
    int c = wn + j * 16 + lm;
    c2a[j] = c2[f * E2 + c];
    c2s[j] = c2[f * E2 + 128 + c];
    wpv[j] = Wp[f * DD + c];
    bpv[j] = bp[f * DD + c];
    fgv[j] = fg[f * DD + c];
    fbev[j] = fbe[f * DD + c];
  }
  for (int i = 0; i < 4; ++i)
    for (int v = 0; v < 4; ++v) {
      int r = wm + i * 16 + lq * 4 + v;
      float xr = x[(size_t)(m0 + r) * FF + f];
      float sum = 0.f, sq = 0.f;
      for (int j = 0; j < 4; ++j) {
        float a = accA[i][j][v] + c2a[j];
        float s = accB[i][j][v] + c2s[j];
        float emb = xr * wpv[j] + bpv[j];
        float y = emb + a / (1.f + expf(-s));
        accA[i][j][v] = y;  // stash y
        sum += y; sq += y * y;
      }
      for (int m = 1; m < 16; m <<= 1) {
        sum += __shfl_xor(sum, m, 64);
        sq += __shfl_xor(sq, m, 64);
      }
      if (lm == 0) { red[w & 1][r][0] = sum; red[w & 1][r][1] = sq; }
    }
  __syncthreads();
  for (int i = 0; i < 4; ++i)
    for (int v = 0; v < 4; ++v) {
      int r = wm + i * 16 + lq * 4 + v;
      float tot = red[0][r][0] + red[1][r][0];
      float totq = red[0][r][1] + red[1][r][1];
      float mu = tot * (1.f / DD);
      float var = totq * (1.f / DD) - mu * mu;
      float rstd = rsqrtf(var + LN_EPS);
      size_t base = ((size_t)(m0 + r) * FF + f) * DD;
      for (int j = 0; j < 4; ++j) {
        int c = wn + j * 16 + lm;
        stacked[base + c] = f2s((accA[i][j][v] - mu) * rstd * fgv[j] + fbev[j]);
      }
    }
}

// ---------------- sgate MFMA: gates = hh1 @ M3 (+c3), tmp = stacked + sa*sigmoid(ss) ----------------
__global__ __launch_bounds__(256) void sgate_mfma(
    const short* __restrict__ hh1, const short* __restrict__ M3T,
    const float* __restrict__ c3, const short* __restrict__ stacked,
    short* __restrict__ tmp) {
  __shared__ short As[128 * 72];
  __shared__ short Ba[64 * 72];
  __shared__ short Bb[64 * 72];
  int m0 = blockIdx.x * 128;
  int c0 = blockIdx.y * 64;
  int tid = threadIdx.x;
  int lane = tid & 63, w = tid >> 6;
  int wm = (w >> 1) * 64, wn = (w & 1) * 32;
  int lm = lane & 15, lq = lane >> 4;
  f32x4 accA[4][2] = {}, accB[4][2] = {};
  for (int kc = 0; kc < 128; kc += 64) {
    for (int i = 0; i < 4; ++i) {
      int li = tid + 256 * i;
      int r = li >> 3, c8 = (li & 7) * 8;
      *(bf16x8*)&As[r * 72 + c8] = *(const bf16x8*)&hh1[(size_t)(m0 + r) * 128 + kc + c8];
    }
    for (int i = 0; i < 2; ++i) {
      int li = tid + 256 * i;
      int r = li >> 3, c8 = (li & 7) * 8;
      *(bf16x8*)&Ba[r * 72 + c8] = *(const bf16x8*)&M3T[(size_t)(c0 + r) * 128 + kc + c8];
      *(bf16x8*)&Bb[r * 72 + c8] = *(const bf16x8*)&M3T[(size_t)(4096 + c0 + r) * 128 + kc + c8];
    }
    __syncthreads();
    for (int ks = 0; ks < 2; ++ks) {
      bf16x8 af[4], ba[2], bb[2];
      for (int i = 0; i < 4; ++i)
        af[i] = *(const bf16x8*)&As[(wm + i * 16 + lm) * 72 + ks * 32 + lq * 8];
      for (int j = 0; j < 2; ++j) {
        ba[j] = *(const bf16x8*)&Ba[(wn + j * 16 + lm) * 72 + ks * 32 + lq * 8];
        bb[j] = *(const bf16x8*)&Bb[(wn + j * 16 + lm) * 72 + ks * 32 + lq * 8];
      }
      for (int i = 0; i < 4; ++i)
        for (int j = 0; j < 2; ++j) {
          accA[i][j] = __builtin_amdgcn_mfma_f32_16x16x32_bf16(af[i], ba[j], accA[i][j], 0, 0, 0);
          accB[i][j] = __builtin_amdgcn_mfma_f32_16x16x32_bf16(af[i], bb[j], accB[i][j], 0, 0, 0);
        }
    }
    __syncthreads();
  }
  for (int i = 0; i < 4; ++i)
    for (int j = 0; j < 2; ++j)
      for (int v = 0; v < 4; ++v) {
        int r = m0 + wm + i * 16 + lq * 4 + v;
        int c = c0 + wn + j * 16 + lm;
        float sa = accA[i][j][v] + c3[c];
        float ss = accB[i][j][v] + c3[c + 4096];
        float g = 1.f / (1.f + expf(-ss));
        tmp[(size_t)r * FD + c] = f2s(s2f(stacked[(size_t)r * FD + c]) + sa * g);
      }
}

// ---------------- LN stats over tmp rows ----------------
__global__ __launch_bounds__(256) void ln_stats2(const short* __restrict__ tmp,
                                                 float* __restrict__ rowstats) {
  int b = blockIdx.x;
  int t = threadIdx.x;
  const short* row = tmp + (size_t)b * FD;
  bf16x8 v0 = *(const bf16x8*)&row[t * 16];
  bf16x8 v1 = *(const bf16x8*)&row[t * 16 + 8];
  float sum = 0.f, sq = 0.f;
  for (int i = 0; i < 8; ++i) {
    float a = s2f(v0[i]), bv = s2f(v1[i]);
    sum += a + bv; sq += a * a + bv * bv;
  }
  for (int off = 32; off; off >>= 1) { sum += __shfl_down(sum, off); sq += __shfl_down(sq, off); }
  __shared__ float rs[4], rq[4];
  int wid = t >> 6;
  if ((t & 63) == 0) { rs[wid] = sum; rq[wid] = sq; }
  __syncthreads();
  if (t == 0) {
    float tot = rs[0] + rs[1] + rs[2] + rs[3];
    float totq = rq[0] + rq[1] + rq[2] + rq[3];
    float mu = tot * (1.f / FD);
    float var = totq * (1.f / FD) - mu * mu;
    rowstats[2 * b] = mu;
    rowstats[2 * b + 1] = rsqrtf(var + LN_EPS);
  }
}

// ---------------- logits GEMM (split-K): partial = tmp @ WhS^T ----------------
__global__ __launch_bounds__(256) void gemm_logits_splitk(
    const short* __restrict__ tmp, const short* __restrict__ WhS,
    float* __restrict__ partial) {
  __shared__ short As[128 * 72];
  __shared__ short Bs[32 * 72];
  int m0 = blockIdx.x * 128;
  int kbase = blockIdx.y * (FD / 4);
  int tid = threadIdx.x;
  int lane = tid & 63, w = tid >> 6;
  int wm = w * 32;
  int lm = lane & 15, lq = lane >> 4;
  f32x4 acc[2][2] = {};
  for (int kc = 0; kc < FD / 4; kc += 64) {
    for (int i = 0; i < 4; ++i) {
      int li = tid + 256 * i;
      int r = li >> 3, c8 = (li & 7) * 8;
      *(bf16x8*)&As[r * 72 + c8] = *(const bf16x8*)&tmp[(size_t)(m0 + r) * FD + kbase + kc + c8];
    }
    {
      int r = tid >> 3, c8 = (tid & 7) * 8;
      *(bf16x8*)&Bs[r * 72 + c8] = *(const bf16x8*)&WhS[(size_t)r * FD + kbase + kc + c8];
    }
    __syncthreads();
    for (int ks = 0; ks < 2; ++ks) {
      bf16x8 af[2], bfr[2];
      for (int i = 0; i < 2; ++i)
        af[i] = *(const bf16x8*)&As[(wm + i * 16 + lm) * 72 + ks * 32 + lq * 8];
      for (int j = 0; j < 2; ++j)
        bfr[j] = *(const bf16x8*)&Bs[(j * 16 + lm) * 72 + ks * 32 + lq * 8];
      for (int i = 0; i < 2; ++i)
        for (int j = 0; j < 2; ++j)
          acc[i][j] = __builtin_amdgcn_mfma_f32_16x16x32_bf16(af[i], bfr[j], acc[i][j], 0, 0, 0);
    }
    __syncthreads();
  }
  for (int i = 0; i < 2; ++i)
    for (int j = 0; j < 2; ++j)
      for (int v = 0; v < 4; ++v) {
        int r = m0 + wm + i * 16 + lq * 4 + v;
        int c = j * 16 + lm;
        partial[(size_t)blockIdx.y * BB * FF + (size_t)r * FF + c] = acc[i][j][v];
      }
}

// ---------------- combine + affine + softmax -> weights ----------------
__global__ void combine_softmax(const float* __restrict__ partial,
                                const float* __restrict__ rowstats,
                                const float* __restrict__ u, const float* __restrict__ w0,
                                float* __restrict__ wfp32, float* __restrict__ outw) {
  int tid = threadIdx.x;
  int b = blockIdx.x * 8 + (tid >> 5);
  int c = tid & 31;
  float s = 0.f;
  for (int p = 0; p < 4; ++p) s += partial[(size_t)p * BB * FF + (size_t)b * FF + c];
  float mu = rowstats[2 * b], rstd = rowstats[2 * b + 1];
  float l = rstd * s - mu * rstd * u[c] + w0[c];
  float m = l;
  for (int off = 16; off; off >>= 1) m = fmaxf(m, __shfl_xor(m, off, 32));
  float e = expf(l - m);
  float ss = e;
  for (int off = 16; off; off >>= 1) ss += __shfl_xor(ss, off, 32);
  float wv = e / ss;
  wfp32[(size_t)b * FF + c] = wv;
  outw[(size_t)b * FF + c] = wv;
}

// ---------------- selected = sum_f stacked[b,f,:]*w[b,f] ----------------
__global__ __launch_bounds__(128) void select_k2(const short* __restrict__ stacked,
                                                 const float* __restrict__ wfp32,
                                                 float* __restrict__ outsel) {
  __shared__ short L[FD];
  __shared__ float wf[FF];
  int b = blockIdx.x;
  int t = threadIdx.x;  // 128
  for (int i = 0; i < 4; ++i) {
    int idx = t + 128 * i;
    *(bf16x8*)&L[idx * 8] = *(const bf16x8*)&stacked[(size_t)b * FD + idx * 8];
  }
  if (t < 32) wf[t] = wfp32[(size_t)b * FF + t];
  __syncthreads();
  float acc = 0.f;
  for (int f = 0; f < FF; ++f) acc += s2f(L[f * 128 + t]) * wf[f];
  outsel[(size_t)b * DD + t] = acc;
}

extern "C" void kernel_launch(void* const* d_in, const int* in_sizes, int n_in,
                              void* d_out, int out_size, void* d_ws, size_t ws_size,
                              hipStream_t stream) {
  const float* x   = (const float*)d_in[0];
  const float* Wp  = (const float*)d_in[1];
  const float* bp  = (const float*)d_in[2];
  const float* fW1 = (const float*)d_in[3];
  const float* fb1 = (const float*)d_in[4];
  const float* fW2 = (const float*)d_in[5];
  const float* fb2 = (const float*)d_in[6];
  const float* fWg = (const float*)d_in[7];
  const float* fbg = (const float*)d_in[8];
  const float* fg  = (const float*)d_in[9];
  const float* fbe = (const float*)d_in[10];
  const float* sW1 = (const float*)d_in[11];
  const float* sb1 = (const float*)d_in[12];
  const float* sW2 = (const float*)d_in[13];
  const float* sb2 = (const float*)d_in[14];
  const float* sWg = (const float*)d_in[15];
  const float* sbg = (const float*)d_in[16];
  const float* sg  = (const float*)d_in[17];
  const float* sbe = (const float*)d_in[18];
  const float* Wh  = (const float*)d_in[19];
  const float* bh  = (const float*)d_in[20];

  float* w = (float*)d_ws;
  size_t off = 0;
  float* A1   = w + off; off += (size_t)FF * HH;
  float* C1   = w + off; off += (size_t)FF * HH;
  float* c2   = w + off; off += (size_t)FF * E2;
  float* c3   = w + off; off += (size_t)F2;
  float* rowstats = w + off; off += (size_t)2 * BB;
  float* u    = w + off; off += 32;
  float* w0   = w + off; off += 32;
  float* wfp32  = w + off; off += (size_t)BB * FF;
  float* M2   = w + off; off += (size_t)FF * HH * E2;              // 4 MB
  float* partial = w + off; off += (size_t)4 * BB * 128;           // 16 MB (split-K, reused)
  short* hh1  = (short*)(w + off); off += (size_t)BB * 128 / 2;    // 2 MB bf16
  short* M3T  = (short*)(w + off); off += (size_t)F2 * 128 / 2;    // 2 MB bf16
  short* sW2b = (short*)(w + off); off += (size_t)128 * FD / 2;    // 1 MB bf16
  short* sW1T = (short*)(w + off); off += (size_t)128 * FD / 2;    // 1 MB bf16
  short* M2T  = (short*)(w + off); off += (size_t)FF * E2 * HH / 2; // 2 MB bf16
  short* WhS  = (short*)(w + off); off += (size_t)FF * FD / 2;     // 256 KB bf16
  short* stacked = (short*)(w + off); off += (size_t)BB * FD / 2;  // 64 MB bf16
  short* tmp  = (short*)(w + off); off += (size_t)BB * FD / 2;     // 64 MB bf16
  short* sWgT = (short*)(w + off); off += (size_t)F2 * FD / 2;     // 64 MB bf16

  float* outsel = (float*)d_out;
  float* outw   = outsel + (size_t)BB * DD;

  // --- prep / casts ---
  cast_bf16<<<(128 * FD + 255) / 256, 256, 0, stream>>>(sW2, sW2b, 128 * FD);
  castT<<<dim3(DD / 64, FD / 64), 256, 0, stream>>>(sW1, sW1T, FD, DD);
  c3_init<<<F2 / 256, 256, 0, stream>>>(sbg, c3);
  castT_c3<<<dim3(F2 / 64, FD / 64), 256, 0, stream>>>(sWg, sWgT, sb2, c3);
  whs_init<<<1, 32, 0, stream>>>(bh, u, w0);
  prep_whs<<<FD / 64, 256, 0, stream>>>(Wh, sg, sbe, WhS, u, w0);
  // --- G1: M3T = (sW2 @ sWg)^T ---
  gemm_bt_n128_splitk<<<dim3(F2 / 128, 4), 256, 0, stream>>>(sWgT, sW2b, partial, F2, FD);
  reduce_m3t<<<(F2 * 128) / 256, 256, 0, stream>>>(partial, M3T, F2);
  // --- per-feature GRN prep + stage A (MFMA) ---
  prep_A1<<<FF, 128, 0, stream>>>(Wp, bp, fW1, fb1, A1, C1);
  prep_M2<<<dim3(FF, HH), E2, 0, stream>>>(fW2, fWg, M2);
  m2_castT<<<dim3(HH / 64, E2 / 64, FF), 256, 0, stream>>>(M2, M2T);
  prep_c2<<<FF, E2, 0, stream>>>(fb2, fWg, fbg, c2);
  stageA_mfma<<<dim3(BB / 128, FF), 256, 0, stream>>>(x, Wp, bp, A1, C1, M2T, c2, fg, fbe,
                                                      stacked);
  // --- G2: hh1 = elu(stacked @ sW1 + sb1) ---
  gemm_bt_n128_splitk<<<dim3(BB / 128, 4), 256, 0, stream>>>(stacked, sW1T, partial, BB, FD);
  reduce_hh1<<<(BB * 128) / 256, 256, 0, stream>>>(partial, sb1, hh1, BB);
  // --- G3: tmp = stacked + sa*sigmoid(ss) ---
  sgate_mfma<<<dim3(BB / 128, FD / 64), 256, 0, stream>>>(hh1, M3T, c3, stacked, tmp);
  // --- LN stats + fused logits GEMM + softmax + select ---
  ln_stats2<<<BB, 256, 0, stream>>>(tmp, rowstats);
  gemm_logits_splitk<<<dim3(BB / 128, 4), 256, 0, stream>>>(tmp, WhS, partial);
  combine_softmax<<<BB / 8, 256, 0, stream>>>(partial, rowstats, u, w0, wfp32, outw);
  select_k2<<<BB, 128, 0, stream>>>(stacked, wfp32, outsel);
}

// Round 7
// 565.124 us; speedup vs baseline: 3.8176x; 1.0940x over previous
//
#include <hip/hip_runtime.h>
#include <hip/hip_bf16.h>
#include <math.h>

#define BB 8192
#define FF 32
#define DD 128
#define HH 128
#define FD 4096   // F*D
#define E2 256    // 2*D
#define F2 8192   // 2*FD
#define LN_EPS 1e-5f
#define L2E 1.44269504f

typedef __hip_bfloat16 bf16;
typedef __attribute__((ext_vector_type(8))) short bf16x8;
typedef __attribute__((ext_vector_type(4))) float f32x4;

__device__ __forceinline__ float s2f(short s) {
  union { float f; unsigned u; } x; x.u = ((unsigned)(unsigned short)s) << 16; return x.f;
}
__device__ __forceinline__ short f2s(float v) {
  bf16 h = __float2bfloat16(v); return *(short*)&h;
}
__device__ __forceinline__ float fast_sigmoid(float s) {
  return __builtin_amdgcn_rcpf(1.f + __builtin_amdgcn_exp2f(-L2E * s));
}
__device__ __forceinline__ float fast_elu(float v) {
  return v > 0.f ? v : __builtin_amdgcn_exp2f(L2E * v) - 1.f;
}

// ---------------- prep kernels (inputs fp32) ----------------

__global__ void prep_A1(const float* __restrict__ Wp, const float* __restrict__ bp,
                        const float* __restrict__ fW1, const float* __restrict__ fb1,
                        float* __restrict__ A1, float* __restrict__ C1) {
  int f = blockIdx.x, h = threadIdx.x;
  const float* w1 = fW1 + (size_t)f * DD * HH;
  float a = 0.f, c = 0.f;
  for (int d = 0; d < DD; ++d) {
    float w = w1[d * HH + h];
    a += Wp[f * DD + d] * w;
    c += bp[f * DD + d] * w;
  }
  A1[f * HH + h] = a;
  C1[f * HH + h] = c + fb1[f * HH + h];
}

__global__ void prep_M2(const float* __restrict__ fW2, const float* __restrict__ fWg,
                        float* __restrict__ M2) {
  int f = blockIdx.x, h = blockIdx.y, e = threadIdx.x;
  const float* w2 = fW2 + ((size_t)f * HH + h) * DD;
  const float* wg = fWg + (size_t)f * DD * E2;
  float acc = 0.f;
  for (int d = 0; d < DD; ++d) acc += w2[d] * wg[d * E2 + e];
  M2[((size_t)f * HH + h) * E2 + e] = acc;
}

// M2 [f][h][e] fp32 -> M2T [f][e][h] bf16
__global__ void m2_castT(const float* __restrict__ M2, short* __restrict__ M2T) {
  __shared__ float T[64][65];
  int h0 = blockIdx.x * 64, e0 = blockIdx.y * 64, f = blockIdx.z;
  int t = threadIdx.x;
  for (int i = 0; i < 16; ++i) {
    int idx = t + 256 * i; int r = idx >> 6, c = idx & 63;
    T[r][c] = M2[((size_t)f * HH + h0 + r) * E2 + e0 + c];
  }
  __syncthreads();
  for (int i = 0; i < 16; ++i) {
    int idx = t + 256 * i; int e = idx >> 6, h = idx & 63;
    M2T[((size_t)f * E2 + e0 + e) * HH + h0 + h] = f2s(T[h][e]);
  }
}

__global__ void prep_c2(const float* __restrict__ fb2, const float* __restrict__ fWg,
                        const float* __restrict__ fbg, float* __restrict__ c2) {
  int f = blockIdx.x, e = threadIdx.x;
  const float* wg = fWg + (size_t)f * DD * E2;
  float acc = 0.f;
  for (int d = 0; d < DD; ++d) acc += fb2[f * DD + d] * wg[d * E2 + e];
  c2[f * E2 + e] = acc + fbg[f * E2 + e];
}

__global__ void cast_bf16(const float* __restrict__ in, short* __restrict__ out, int n) {
  int i = blockIdx.x * 256 + threadIdx.x;
  if (i < n) out[i] = f2s(in[i]);
}

// transpose-cast: in (R x C) fp32 -> out (C x R) bf16
__global__ void castT(const float* __restrict__ in, short* __restrict__ out, int R, int C) {
  __shared__ float T[64][65];
  int c0 = blockIdx.x * 64, r0 = blockIdx.y * 64;
  int t = threadIdx.x;
  for (int i = 0; i < 16; ++i) {
    int idx = t + 256 * i; int r = idx >> 6, c = idx & 63;
    T[r][c] = in[(size_t)(r0 + r) * C + c0 + c];
  }
  __syncthreads();
  for (int i = 0; i < 16; ++i) {
    int idx = t + 256 * i; int c = idx >> 6, r = idx & 63;
    out[(size_t)(c0 + c) * R + r0 + r] = f2s(T[r][c]);
  }
}

// merged tiny inits: c3 = sbg; u = 0; w0 = bh
__global__ void init_misc(const float* __restrict__ sbg, const float* __restrict__ bh,
                          float* __restrict__ c3, float* __restrict__ u,
                          float* __restrict__ w0) {
  int j = blockIdx.x * 256 + threadIdx.x;
  c3[j] = sbg[j];
  if (j < 32) { u[j] = 0.f; w0[j] = bh[j]; }
}

// transpose-cast sWg (4096 x 8192) -> sWgT (8192 x 4096) bf16, fused c3 += sb2 @ sWg
__global__ void castT_c3(const float* __restrict__ in, short* __restrict__ out,
                         const float* __restrict__ sb2, float* __restrict__ c3) {
  __shared__ float T[64][65];
  int c0 = blockIdx.x * 64, r0 = blockIdx.y * 64;
  int t = threadIdx.x;
  for (int i = 0; i < 16; ++i) {
    int idx = t + 256 * i; int r = idx >> 6, c = idx & 63;
    T[r][c] = in[(size_t)(r0 + r) * F2 + c0 + c];
  }
  __syncthreads();
  for (int i = 0; i < 16; ++i) {
    int idx = t + 256 * i; int c = idx >> 6, r = idx & 63;
    out[(size_t)(c0 + c) * FD + r0 + r] = f2s(T[r][c]);
  }
  if (t < 64) {
    float s = 0.f;
    for (int r = 0; r < 64; ++r) s += sb2[r0 + r] * T[r][t];
    atomicAdd(&c3[c0 + t], s);
  }
}

// WhS = (sg*Wh)^T bf16; u += sg.Wh col-sums; w0 += sbe.Wh col-sums
__global__ void prep_whs(const float* __restrict__ Wh, const float* __restrict__ sg,
                         const float* __restrict__ sbe, short* __restrict__ WhS,
                         float* __restrict__ u, float* __restrict__ w0) {
  __shared__ float T[64][33];
  int k0 = blockIdx.x * 64;
  int t = threadIdx.x;
  {
    int k = t >> 5, c = t & 31;
    for (int i = 0; i < 8; ++i)
      T[k + 8 * i][c] = Wh[(size_t)(k0 + k + 8 * i) * FF + c];
  }
  __syncthreads();
  {
    int c = t >> 3, kk = (t & 7) * 8;
    short o[8];
    for (int i = 0; i < 8; ++i) o[i] = f2s(sg[k0 + kk + i] * T[kk + i][c]);
    *(bf16x8*)&WhS[(size_t)c * FD + k0 + kk] = *(bf16x8*)&o[0];
  }
  if (t < 32) {
    float su = 0.f, sw = 0.f;
    for (int k = 0; k < 64; ++k) { su += sg[k0 + k] * T[k][t]; sw += sbe[k0 + k] * T[k][t]; }
    atomicAdd(&u[t], su);
    atomicAdd(&w0[t], sw);
  }
}

// ---------------- MFMA GEMM: C[M,128] = A[M,K] @ BT[128,K]^T, split-K by 4 ----------------
__global__ __launch_bounds__(256) void gemm_bt_n128_splitk(
    const short* __restrict__ A, const short* __restrict__ BT,
    float* __restrict__ Cp, int M, int K) {
  __shared__ short As[128 * 72];
  __shared__ short Bs[128 * 72];
  int m0 = blockIdx.x * 128;
  int kchunk = K >> 2;
  int kbase = blockIdx.y * kchunk;
  int tid = threadIdx.x;
  int lane = tid & 63, w = tid >> 6;
  int wm = (w >> 1) * 64, wn = (w & 1) * 64;
  int lm = lane & 15, lq = lane >> 4;
  f32x4 acc[4][4] = {};
  for (int kc = 0; kc < kchunk; kc += 64) {
    for (int i = 0; i < 4; ++i) {
      int li = tid + 256 * i;
      int r = li >> 3, c8 = (li & 7) * 8;
      *(bf16x8*)&As[r * 72 + c8] = *(const bf16x8*)&A[(size_t)(m0 + r) * K + kbase + kc + c8];
      *(bf16x8*)&Bs[r * 72 + c8] = *(const bf16x8*)&BT[(size_t)r * K + kbase + kc + c8];
    }
    __syncthreads();
    for (int ks = 0; ks < 2; ++ks) {
      bf16x8 af[4], bfr[4];
      for (int i = 0; i < 4; ++i)
        af[i] = *(const bf16x8*)&As[(wm + i * 16 + lm) * 72 + ks * 32 + lq * 8];
      for (int j = 0; j < 4; ++j)
        bfr[j] = *(const bf16x8*)&Bs[(wn + j * 16 + lm) * 72 + ks * 32 + lq * 8];
      for (int i = 0; i < 4; ++i)
        for (int j = 0; j < 4; ++j)
          acc[i][j] = __builtin_amdgcn_mfma_f32_16x16x32_bf16(af[i], bfr[j], acc[i][j], 0, 0, 0);
    }
    __syncthreads();
  }
  float* out = Cp + (size_t)blockIdx.y * M * 128;
  for (int i = 0; i < 4; ++i)
    for (int j = 0; j < 4; ++j)
      for (int v = 0; v < 4; ++v) {
        int r = wm + i * 16 + lq * 4 + v;
        int c = wn + j * 16 + lm;
        out[(size_t)(m0 + r) * 128 + c] = acc[i][j][v];
      }
}

__global__ void reduce_m3t(const float* __restrict__ Cp, short* __restrict__ M3T, int M) {
  size_t i = (size_t)blockIdx.x * 256 + threadIdx.x;
  float s = 0.f;
  for (int k = 0; k < 4; ++k) s += Cp[(size_t)k * M * 128 + i];
  M3T[i] = f2s(s);
}

__global__ void reduce_hh1(const float* __restrict__ Cp, const float* __restrict__ sb1,
                           short* __restrict__ hh1, int M) {
  size_t i = (size_t)blockIdx.x * 256 + threadIdx.x;
  float s = 0.f;
  for (int k = 0; k < 4; ++k) s += Cp[(size_t)k * M * 128 + i];
  s += sb1[i & 127];
  hh1[i] = f2s(fast_elu(s));
}

// ---------------- stage A (MFMA): h1 = elu(x*A1+C1); gates = h1@M2; LN -> stacked ----------------
__global__ __launch_bounds__(256) void stageA_mfma(
    const float* __restrict__ x, const float* __restrict__ Wp,
    const float* __restrict__ bp, const float* __restrict__ A1,
    const float* __restrict__ C1, const short* __restrict__ M2T,
    const float* __restrict__ c2, const float* __restrict__ fg,
    const float* __restrict__ fbe, short* __restrict__ stacked) {
  __shared__ __align__(16) char SM[3 * 128 * 72 * 2];  // As | Ba | Bb ; Co aliases Ba+Bb
  short* As = (short*)SM;
  short* Ba = (short*)(SM + 128 * 72 * 2);
  short* Bb = (short*)(SM + 2 * 128 * 72 * 2);
  short* Co = (short*)(SM + 128 * 72 * 2);  // 128x128 bf16 epilogue tile (32KB <= 36KB)
  __shared__ float xsh[128];
  __shared__ float red[2][128][2];
  int f = blockIdx.y;
  int m0 = blockIdx.x * 128;
  int tid = threadIdx.x;
  int lane = tid & 63, w = tid >> 6;
  int wm = (w >> 1) * 64, wn = (w & 1) * 64;
  int lm = lane & 15, lq = lane >> 4;
  if (tid < 128) xsh[tid] = x[(size_t)(m0 + tid) * FF + f];
  __syncthreads();
  f32x4 accA[4][4] = {}, accB[4][4] = {};
  for (int kc = 0; kc < HH; kc += 64) {
    {
      int r = tid >> 1;
      int hcb = (tid & 1) * 32;
      float xr = xsh[r];
      const float* a1p = A1 + f * HH + kc + hcb;
      const float* c1p = C1 + f * HH + kc + hcb;
      short* dst = &As[r * 72 + hcb];
      for (int s = 0; s < 32; ++s) {
        float v = fmaf(xr, a1p[s], c1p[s]);
        dst[s] = f2s(fast_elu(v));
      }
    }
    for (int i = 0; i < 4; ++i) {
      int li = tid + 256 * i;
      int rr = li >> 3, c8 = (li & 7) * 8;
      *(bf16x8*)&Ba[rr * 72 + c8] = *(const bf16x8*)&M2T[((size_t)f * E2 + rr) * HH + kc + c8];
      *(bf16x8*)&Bb[rr * 72 + c8] = *(const bf16x8*)&M2T[((size_t)f * E2 + 128 + rr) * HH + kc + c8];
    }
    __syncthreads();
    for (int ks = 0; ks < 2; ++ks) {
      bf16x8 af[4], ba[4], bb[4];
      for (int i = 0; i < 4; ++i)
        af[i] = *(const bf16x8*)&As[(wm + i * 16 + lm) * 72 + ks * 32 + lq * 8];
      for (int j = 0; j < 4; ++j) {
        ba[j] = *(const bf16x8*)&Ba[(wn + j * 16 + lm) * 72 + ks * 32 + lq * 8];
        bb[j] = *(const bf16x8*)&Bb[(wn + j * 16 + lm) * 72 + ks * 32 + lq * 8];
      }
      for (int i = 0; i < 4; ++i)
        for (int j = 0; j < 4; ++j) {
          accA[i][j] = __builtin_amdgcn_mfma_f32_16x16x32_bf16(af[i], ba[j], accA[i][j], 0, 0, 0);
          accB[i][j] = __builtin_amdgcn_mfma_f32_16x16x32_bf16(af[i], bb[j], accB[i][j], 0, 0, 0);
        }
    }
    __syncthreads();
  }
  // epilogue: gating + LN stats
  float c2a[4], c2s[4], wpv[4], bpv[4];
  for (int j = 0; j < 4; ++j) {
    int c = wn + j * 16 + lm;
    c2a[j] = c2[f * E2 + c];
    c2s[j] = c2[f * E2 + 128 + c];
    wpv[j] = Wp[f * DD + c];
    bpv[j] = bp[f * DD + c];
  }
  for (int i = 0; i < 4; ++i)
    for (int v = 0; v < 4; ++v) {
      int r = wm + i * 16 + lq * 4 + v;
      float xr = xsh[r];
      float sum = 0.f, sq = 0.f;
      for (int j = 0; j < 4; ++j) {
        float a = accA[i][j][v] + c2a[j];
        float s = accB[i][j][v] + c2s[j];
        float emb = fmaf(xr, wpv[j], bpv[j]);
        float y = fmaf(a, fast_sigmoid(s), emb);
        accA[i][j][v] = y;  // stash y
        sum += y; sq += y * y;
      }
      for (int m = 1; m < 16; m <<= 1) {
        sum += __shfl_xor(sum, m, 64);
        sq += __shfl_xor(sq, m, 64);
      }
      if (lm == 0) { red[w & 1][r][0] = sum; red[w & 1][r][1] = sq; }
    }
  __syncthreads();
  float fgv[4], fbev[4];
  for (int j = 0; j < 4; ++j) {
    int c = wn + j * 16 + lm;
    fgv[j] = fg[f * DD + c];
    fbev[j] = fbe[f * DD + c];
  }
  for (int i = 0; i < 4; ++i)
    for (int v = 0; v < 4; ++v) {
      int r = wm + i * 16 + lq * 4 + v;
      float tot = red[0][r][0] + red[1][r][0];
      float totq = red[0][r][1] + red[1][r][1];
      float mu = tot * (1.f / DD);
      float var = totq * (1.f / DD) - mu * mu;
      float rstd = rsqrtf(var + LN_EPS);
      for (int j = 0; j < 4; ++j) {
        int c = wn + j * 16 + lm;
        Co[r * 128 + c] = f2s((accA[i][j][v] - mu) * rstd * fgv[j] + fbev[j]);
      }
    }
  __syncthreads();
  for (int i = 0; i < 8; ++i) {
    int lin = tid + 256 * i;
    int r = lin >> 4, c8 = (lin & 15) * 8;
    *(bf16x8*)&stacked[((size_t)(m0 + r) * FF + f) * DD + c8] = *(bf16x8*)&Co[r * 128 + c8];
  }
}

// ---------------- sgate MFMA: gates = hh1 @ M3 (+c3), tmp = stacked + sa*sigmoid(ss) ----------------
__global__ __launch_bounds__(256) void sgate_mfma(
    const short* __restrict__ hh1, const short* __restrict__ M3T,
    const float* __restrict__ c3, const short* __restrict__ stacked,
    short* __restrict__ tmp) {
  __shared__ short As[128 * 72];
  __shared__ short Ba[64 * 72];
  __shared__ short Bb[64 * 72];
  short* Co = As;  // epilogue alias: 128x64 bf16 tile (16KB <= 18KB)
  int m0 = blockIdx.x * 128;
  int c0 = blockIdx.y * 64;
  int tid = threadIdx.x;
  int lane = tid & 63, w = tid >> 6;
  int wm = (w >> 1) * 64, wn = (w & 1) * 32;
  int lm = lane & 15, lq = lane >> 4;
  f32x4 accA[4][2] = {}, accB[4][2] = {};
  for (int kc = 0; kc < 128; kc += 64) {
    for (int i = 0; i < 4; ++i) {
      int li = tid + 256 * i;
      int r = li >> 3, c8 = (li & 7) * 8;
      *(bf16x8*)&As[r * 72 + c8] = *(const bf16x8*)&hh1[(size_t)(m0 + r) * 128 + kc + c8];
    }
    for (int i = 0; i < 2; ++i) {
      int li = tid + 256 * i;
      int r = li >> 3, c8 = (li & 7) * 8;
      *(bf16x8*)&Ba[r * 72 + c8] = *(const bf16x8*)&M3T[(size_t)(c0 + r) * 128 + kc + c8];
      *(bf16x8*)&Bb[r * 72 + c8] = *(const bf16x8*)&M3T[(size_t)(4096 + c0 + r) * 128 + kc + c8];
    }
    __syncthreads();
    for (int ks = 0; ks < 2; ++ks) {
      bf16x8 af[4], ba[2], bb[2];
      for (int i = 0; i < 4; ++i)
        af[i] = *(const bf16x8*)&As[(wm + i * 16 + lm) * 72 + ks * 32 + lq * 8];
      for (int j = 0; j < 2; ++j) {
        ba[j] = *(const bf16x8*)&Ba[(wn + j * 16 + lm) * 72 + ks * 32 + lq * 8];
        bb[j] = *(const bf16x8*)&Bb[(wn + j * 16 + lm) * 72 + ks * 32 + lq * 8];
      }
      for (int i = 0; i < 4; ++i)
        for (int j = 0; j < 2; ++j) {
          accA[i][j] = __builtin_amdgcn_mfma_f32_16x16x32_bf16(af[i], ba[j], accA[i][j], 0, 0, 0);
          accB[i][j] = __builtin_amdgcn_mfma_f32_16x16x32_bf16(af[i], bb[j], accB[i][j], 0, 0, 0);
        }
    }
    __syncthreads();
  }
  // epilogue: gate term -> LDS (bf16), then coalesced RMW of tmp
  for (int i = 0; i < 4; ++i)
    for (int j = 0; j < 2; ++j)
      for (int v = 0; v < 4; ++v) {
        int rl = wm + i * 16 + lq * 4 + v;
        int cl = wn + j * 16 + lm;
        int c = c0 + cl;
        float sa = accA[i][j][v] + c3[c];
        float ss = accB[i][j][v] + c3[c + 4096];
        Co[rl * 64 + cl] = f2s(sa * fast_sigmoid(ss));
      }
  __syncthreads();
  for (int i = 0; i < 4; ++i) {
    int lin = tid + 256 * i;
    int r = lin >> 3, c8 = (lin & 7) * 8;
    size_t gi = (size_t)(m0 + r) * FD + c0 + c8;
    bf16x8 sv = *(const bf16x8*)&stacked[gi];
    bf16x8 av = *(bf16x8*)&Co[r * 64 + c8];
    short ov[8];
    for (int e = 0; e < 8; ++e) ov[e] = f2s(s2f(sv[e]) + s2f(av[e]));
    *(bf16x8*)&tmp[gi] = *(bf16x8*)&ov[0];
  }
}

// ---------------- LN stats over tmp rows ----------------
__global__ __launch_bounds__(256) void ln_stats2(const short* __restrict__ tmp,
                                                 float* __restrict__ rowstats) {
  int b = blockIdx.x;
  int t = threadIdx.x;
  const short* row = tmp + (size_t)b * FD;
  bf16x8 v0 = *(const bf16x8*)&row[t * 16];
  bf16x8 v1 = *(const bf16x8*)&row[t * 16 + 8];
  float sum = 0.f, sq = 0.f;
  for (int i = 0; i < 8; ++i) {
    float a = s2f(v0[i]), bv = s2f(v1[i]);
    sum += a + bv; sq += a * a + bv * bv;
  }
  for (int off = 32; off; off >>= 1) { sum += __shfl_down(sum, off); sq += __shfl_down(sq, off); }
  __shared__ float rs[4], rq[4];
  int wid = t >> 6;
  if ((t & 63) == 0) { rs[wid] = sum; rq[wid] = sq; }
  __syncthreads();
  if (t == 0) {
    float tot = rs[0] + rs[1] + rs[2] + rs[3];
    float totq = rq[0] + rq[1] + rq[2] + rq[3];
    float mu = tot * (1.f / FD);
    float var = totq * (1.f / FD) - mu * mu;
    rowstats[2 * b] = mu;
    rowstats[2 * b + 1] = rsqrtf(var + LN_EPS);
  }
}

// ---------------- logits GEMM (split-K): partial = tmp @ WhS^T ----------------
__global__ __launch_bounds__(256) void gemm_logits_splitk(
    const short* __restrict__ tmp, const short* __restrict__ WhS,
    float* __restrict__ partial) {
  __shared__ short As[128 * 72];
  __shared__ short Bs[32 * 72];
  int m0 = blockIdx.x * 128;
  int kbase = blockIdx.y * (FD / 4);
  int tid = threadIdx.x;
  int lane = tid & 63, w = tid >> 6;
  int wm = w * 32;
  int lm = lane & 15, lq = lane >> 4;
  f32x4 acc[2][2] = {};
  for (int kc = 0; kc < FD / 4; kc += 64) {
    for (int i = 0; i < 4; ++i) {
      int li = tid + 256 * i;
      int r = li >> 3, c8 = (li & 7) * 8;
      *(bf16x8*)&As[r * 72 + c8] = *(const bf16x8*)&tmp[(size_t)(m0 + r) * FD + kbase + kc + c8];
    }
    {
      int r = tid >> 3, c8 = (tid & 7) * 8;
      *(bf16x8*)&Bs[r * 72 + c8] = *(const bf16x8*)&WhS[(size_t)r * FD + kbase + kc + c8];
    }
    __syncthreads();
    for (int ks = 0; ks < 2; ++ks) {
      bf16x8 af[2], bfr[2];
      for (int i = 0; i < 2; ++i)
        af[i] = *(const bf16x8*)&As[(wm + i * 16 + lm) * 72 + ks * 32 + lq * 8];
      for (int j = 0; j < 2; ++j)
        bfr[j] = *(const bf16x8*)&Bs[(j * 16 + lm) * 72 + ks * 32 + lq * 8];
      for (int i = 0; i < 2; ++i)
        for (int j = 0; j < 2; ++j)
          acc[i][j] = __builtin_amdgcn_mfma_f32_16x16x32_bf16(af[i], bfr[j], acc[i][j], 0, 0, 0);
    }
    __syncthreads();
  }
  for (int i = 0; i < 2; ++i)
    for (int j = 0; j < 2; ++j)
      for (int v = 0; v < 4; ++v) {
        int r = m0 + wm + i * 16 + lq * 4 + v;
        int c = j * 16 + lm;
        partial[(size_t)blockIdx.y * BB * FF + (size_t)r * FF + c] = acc[i][j][v];
      }
}

// ---------------- fused: combine partials + affine + softmax + weighted select ----------------
__global__ __launch_bounds__(128) void select_fused(
    const float* __restrict__ partial, const float* __restrict__ rowstats,
    const float* __restrict__ u, const float* __restrict__ w0,
    const short* __restrict__ stacked, float* __restrict__ outsel,
    float* __restrict__ outw) {
  __shared__ float wf[FF];
  __shared__ short L[FD];
  int b = blockIdx.x;
  int t = threadIdx.x;
  for (int i = 0; i < 4; ++i) {
    int idx = t + 128 * i;
    *(bf16x8*)&L[idx * 8] = *(const bf16x8*)&stacked[(size_t)b * FD + idx * 8];
  }
  if (t < 32) {
    float s = 0.f;
    for (int p = 0; p < 4; ++p) s += partial[(size_t)p * BB * FF + (size_t)b * FF + t];
    float mu = rowstats[2 * b], rstd = rowstats[2 * b + 1];
    float l = rstd * s - mu * rstd * u[t] + w0[t];
    float m = l;
    for (int off = 16; off; off >>= 1) m = fmaxf(m, __shfl_xor(m, off, 32));
    float e = __builtin_amdgcn_exp2f(L2E * (l - m));
    float ss = e;
    for (int off = 16; off; off >>= 1) ss += __shfl_xor(ss, off, 32);
    float wv = e / ss;
    wf[t] = wv;
    outw[(size_t)b * FF + t] = wv;
  }
  __syncthreads();
  float acc = 0.f;
  for (int ff = 0; ff < FF; ++ff) acc += s2f(L[ff * 128 + t]) * wf[ff];
  outsel[(size_t)b * DD + t] = acc;
}

extern "C" void kernel_launch(void* const* d_in, const int* in_sizes, int n_in,
                              void* d_out, int out_size, void* d_ws, size_t ws_size,
                              hipStream_t stream) {
  const float* x   = (const float*)d_in[0];
  const float* Wp  = (const float*)d_in[1];
  const float* bp  = (const float*)d_in[2];
  const float* fW1 = (const float*)d_in[3];
  const float* fb1 = (const float*)d_in[4];
  const float* fW2 = (const float*)d_in[5];
  const float* fb2 = (const float*)d_in[6];
  const float* fWg = (const float*)d_in[7];
  const float* fbg = (const float*)d_in[8];
  const float* fg  = (const float*)d_in[9];
  const float* fbe = (const float*)d_in[10];
  const float* sW1 = (const float*)d_in[11];
  const float* sb1 = (const float*)d_in[12];
  const float* sW2 = (const float*)d_in[13];
  const float* sb2 = (const float*)d_in[14];
  const float* sWg = (const float*)d_in[15];
  const float* sbg = (const float*)d_in[16];
  const float* sg  = (const float*)d_in[17];
  const float* sbe = (const float*)d_in[18];
  const float* Wh  = (const float*)d_in[19];
  const float* bh  = (const float*)d_in[20];

  float* w = (float*)d_ws;
  size_t off = 0;
  float* A1   = w + off; off += (size_t)FF * HH;
  float* C1   = w + off; off += (size_t)FF * HH;
  float* c2   = w + off; off += (size_t)FF * E2;
  float* c3   = w + off; off += (size_t)F2;
  float* rowstats = w + off; off += (size_t)2 * BB;
  float* u    = w + off; off += 32;
  float* w0   = w + off; off += 32;
  float* M2   = w + off; off += (size_t)FF * HH * E2;               // 4 MB
  float* partial = w + off; off += (size_t)4 * BB * 128;            // 16 MB
  short* hh1  = (short*)(w + off); off += (size_t)BB * 128 / 2;     // 2 MB
  short* M3T  = (short*)(w + off); off += (size_t)F2 * 128 / 2;     // 2 MB
  short* sW2b = (short*)(w + off); off += (size_t)128 * FD / 2;     // 1 MB
  short* sW1T = (short*)(w + off); off += (size_t)128 * FD / 2;     // 1 MB
  short* M2T  = (short*)(w + off); off += (size_t)FF * E2 * HH / 2; // 2 MB
  short* WhS  = (short*)(w + off); off += (size_t)FF * FD / 2;      // 256 KB
  short* stacked = (short*)(w + off); off += (size_t)BB * FD / 2;   // 64 MB
  short* tmp  = (short*)(w + off); off += (size_t)BB * FD / 2;      // 64 MB
  short* sWgT = (short*)(w + off); off += (size_t)F2 * FD / 2;      // 64 MB

  float* outsel = (float*)d_out;
  float* outw   = outsel + (size_t)BB * DD;

  // --- prep / casts ---
  cast_bf16<<<(128 * FD + 255) / 256, 256, 0, stream>>>(sW2, sW2b, 128 * FD);
  castT<<<dim3(DD / 64, FD / 64), 256, 0, stream>>>(sW1, sW1T, FD, DD);
  init_misc<<<F2 / 256, 256, 0, stream>>>(sbg, bh, c3, u, w0);
  castT_c3<<<dim3(F2 / 64, FD / 64), 256, 0, stream>>>(sWg, sWgT, sb2, c3);
  prep_whs<<<FD / 64, 256, 0, stream>>>(Wh, sg, sbe, WhS, u, w0);
  // --- G1: M3T = (sW2 @ sWg)^T ---
  gemm_bt_n128_splitk<<<dim3(F2 / 128, 4), 256, 0, stream>>>(sWgT, sW2b, partial, F2, FD);
  reduce_m3t<<<(F2 * 128) / 256, 256, 0, stream>>>(partial, M3T, F2);
  // --- per-feature GRN prep + stage A (MFMA) ---
  prep_A1<<<FF, 128, 0, stream>>>(Wp, bp, fW1, fb1, A1, C1);
  prep_M2<<<dim3(FF, HH), E2, 0, stream>>>(fW2, fWg, M2);
  m2_castT<<<dim3(HH / 64, E2 / 64, FF), 256, 0, stream>>>(M2, M2T);
  prep_c2<<<FF, E2, 0, stream>>>(fb2, fWg, fbg, c2);
  stageA_mfma<<<dim3(BB / 128, FF), 256, 0, stream>>>(x, Wp, bp, A1, C1, M2T, c2, fg, fbe,
                                                      stacked);
  // --- G2: hh1 = elu(stacked @ sW1 + sb1) ---
  gemm_bt_n128_splitk<<<dim3(BB / 128, 4), 256, 0, stream>>>(stacked, sW1T, partial, BB, FD);
  reduce_hh1<<<(BB * 128) / 256, 256, 0, stream>>>(partial, sb1, hh1, BB);
  // --- G3: tmp = stacked + sa*sigmoid(ss) ---
  sgate_mfma<<<dim3(BB / 128, FD / 64), 256, 0, stream>>>(hh1, M3T, c3, stacked, tmp);
  // --- LN stats + logits GEMM + fused softmax/select ---
  ln_stats2<<<BB, 256, 0, stream>>>(tmp, rowstats);
  gemm_logits_splitk<<<dim3(BB / 128, 4), 256, 0, stream>>>(tmp, WhS, partial);
  select_fused<<<BB, 128, 0, stream>>>(partial, rowstats, u, w0, stacked, outsel, outw);
}